// Round 1
// 306.919 us; speedup vs baseline: 1.1431x; 1.1431x over previous
//
#include <hip/hip_runtime.h>
#include <math.h>

#define PI_F 3.14159265358979323846f

__device__ __forceinline__ float gelu_f(float x){ return 0.5f*x*(1.0f+erff(x*0.7071067811865475f)); }
__device__ __forceinline__ float sigm_f(float x){ return 1.0f/(1.0f+expf(-x)); }

// B=8, H=W=64, HW=4096, NP=32768, FC=768, RC=8, P=8, K=9, G=8 channel groups

// ---------------- K1: fp1 1x1 conv 768->8, channel-split partials ----------------
__global__ void __launch_bounds__(256) k_conv1(const float* __restrict__ fm,
                        const float* __restrict__ w1, float* __restrict__ part){
    int chunk = blockIdx.x;   // 0..31
    int g = blockIdx.y;       // 0..7 (96 ch each)
    int tid = threadIdx.x;
    __shared__ float wl[96*8];
    for (int i=tid;i<96*8;i+=256){ int c=i>>3, co=i&7; wl[i]=w1[co*768 + g*96 + c]; }
    __syncthreads();
    int b = chunk>>2;
    int q0 = ((chunk&3)<<8) + tid;   // f4 offset within batch plane (0..1023)
    const float4* fm4 = (const float4*)fm;
    float4 acc[8];
    #pragma unroll
    for(int co=0;co<8;co++) acc[co]=make_float4(0.f,0.f,0.f,0.f);
    int basec = b*768 + g*96;
    for(int c=0;c<96;c++){
        float4 x = fm4[(size_t)(basec+c)*1024 + q0];
        #pragma unroll
        for(int co=0;co<8;co++){
            float wv = wl[(c<<3)+co];
            acc[co].x += wv*x.x; acc[co].y += wv*x.y; acc[co].z += wv*x.z; acc[co].w += wv*x.w;
        }
    }
    float4* p4 = (float4*)part;
    int gq = (b<<10) + q0;
    #pragma unroll
    for(int co=0;co<8;co++) p4[(size_t)(g*8+co)*8192 + gq] = acc[co];
}

// ---------------- k_bank: build normalized ridge bank once ----------------
__global__ void __launch_bounds__(256) k_bank(const float* __restrict__ pd,
                                              float* __restrict__ klg){
    __shared__ float ridge[648];
    __shared__ float pmS[8], pdenS[8];
    int tid = threadIdx.x;
    for(int t=tid;t<648;t+=256){
        int p=t/81, idx=t-p*81;
        int i=idx/9, j=idx-i*9;
        float ay=-1.f+0.25f*(float)i;
        float ax=-1.f+0.25f*(float)j;
        float ang=2.f*PI_F*(float)p*0.125f;
        const float Ls[3]={0.45f,0.75f,1.05f};
        const float Ws[3]={0.14f,0.20f,0.28f};
        float L=Ls[p%3], Wd=Ws[(p/3)%3];
        float cs=cosf(ang), sn=sinf(ang);
        float xr=ax*cs+ay*sn;
        float yr=-ax*sn+ay*cs;
        float tp=1.f-fminf(fabsf(xr)/L,1.f);
        float taper=powf(tp,1.5f);
        float core=expf(-0.5f*((xr/L)*(xr/L)+(yr/Wd)*(yr/Wd)));
        ridge[t]=taper*core*fmaxf(1.f-(yr/Wd)*(yr/Wd),0.f);
    }
    __syncthreads();
    {
        int p=tid>>5, k=tid&31;
        float s=0.f;
        for(int e=k;e<81;e+=32) s+=ridge[p*81+e];
        for(int off=16;off>0;off>>=1) s+=__shfl_down(s,off,32);
        if(k==0) pmS[p]=s*(1.f/81.f);
    }
    __syncthreads();
    {
        int p=tid>>5, k=tid&31;
        float m=pmS[p];
        float s=0.f;
        for(int e=k;e<81;e+=32) s+=fabsf(ridge[p*81+e]-m);
        for(int off=16;off>0;off>>=1) s+=__shfl_down(s,off,32);
        if(k==0) pdenS[p]=fmaxf(s,1e-6f);
    }
    __syncthreads();
    for(int t=tid;t<648;t+=256){
        int p=t/81;
        klg[t]=(ridge[t]-pmS[p])/pdenS[p]+0.05f*pd[t];
    }
}

// ---------------- k_comb: sum 8 partials + bias + gelu -> t1 (in place, g=0 planes) ----------------
__global__ void __launch_bounds__(256) k_comb(float* __restrict__ part,
                                              const float* __restrict__ b1){
    int idx = blockIdx.x*256 + threadIdx.x;   // 0..65535 f4 outputs
    int co = idx>>13, rem = idx&8191;          // rem = b*1024 + q
    float4* p4 = (float4*)part;
    float4 s = make_float4(0.f,0.f,0.f,0.f);
    #pragma unroll
    for(int g=0;g<8;g++){
        float4 v = p4[(size_t)((g<<3)+co)*8192 + rem];
        s.x+=v.x; s.y+=v.y; s.z+=v.z; s.w+=v.w;
    }
    float bb=b1[co];
    s.x=gelu_f(s.x+bb); s.y=gelu_f(s.y+bb); s.z=gelu_f(s.z+bb); s.w=gelu_f(s.w+bb);
    p4[(size_t)co*8192 + rem] = s;   // same thread read this addr (g=0) above: safe
}

// ---------------- k_conv2: 3x3 conv 8->8 + gelu -> carrier, cm, absc, absc-stats ----------------
// grid 256: bl = b*32+band, band = 2 output rows
__global__ void __launch_bounds__(256) k_conv2(const float* __restrict__ t1,
    const float* __restrict__ w2, const float* __restrict__ b2,
    float* __restrict__ carrier, float* __restrict__ cm, float* __restrict__ absc,
    float* __restrict__ bpart){
    __shared__ float t1T[8][256];    // rows y0-1..y0+2
    __shared__ float w2s[576];
    __shared__ float sumS[2][128];
    __shared__ float saS[2][128];
    __shared__ float rS[256], rMn[256], rMx[256];
    int tid=threadIdx.x, bl=blockIdx.x;
    int b=bl>>5, band=bl&31, y0=band<<1;
    for(int i=tid;i<576;i+=256) w2s[i]=w2[i];
    {
        int r=tid>>6, x=tid&63;
        int gy=y0-1+r;
        bool ok = (gy>=0 && gy<64);
        int base = (b<<12)+(gy<<6)+x;
        #pragma unroll
        for(int co=0;co<8;co++)
            t1T[co][tid] = ok ? t1[co*32768 + base] : 0.f;
    }
    __syncthreads();
    int px=tid&127, half=tid>>7;
    int ly=px>>6, x=px&63, gy=y0+ly;
    float acc[4];
    #pragma unroll
    for(int qq=0;qq<4;qq++) acc[qq]=b2[half*4+qq];
    for(int ci=0;ci<8;ci++){
        #pragma unroll
        for(int dy=-1;dy<=1;dy++){
            int tr=ly+1+dy;
            #pragma unroll
            for(int dx=-1;dx<=1;dx++){
                int xx=x+dx;
                float v=(xx>=0&&xx<64)?t1T[ci][tr*64+xx]:0.f;
                int ti=(dy+1)*3+(dx+1);
                #pragma unroll
                for(int qq=0;qq<4;qq++) acc[qq]+=v*w2s[((half*4+qq)*8+ci)*9+ti];
            }
        }
    }
    float s4=0.f, sa4=0.f;
    #pragma unroll
    for(int qq=0;qq<4;qq++){
        float cv=gelu_f(acc[qq]);
        carrier[((size_t)((b<<3)+half*4+qq)<<12)+(gy<<6)+x]=cv;
        s4+=cv; sa4+=fabsf(cv);
    }
    sumS[half][px]=s4; saS[half][px]=sa4;
    __syncthreads();
    float aS=0.f, aMn=1e30f, aMx=-1e30f;
    if(half==0){
        float cmv=(sumS[0][px]+sumS[1][px])*0.125f;
        float av =(saS[0][px]+saS[1][px])*0.125f;
        int gp=(b<<12)+(gy<<6)+x;
        cm[gp]=cmv;
        absc[gp]=av;
        aS=av; aMn=av; aMx=av;
    }
    rS[tid]=aS; rMn[tid]=aMn; rMx[tid]=aMx;
    __syncthreads();
    for(int st=128;st>0;st>>=1){
        if(tid<st){
            rS[tid]+=rS[tid+st];
            rMn[tid]=fminf(rMn[tid],rMn[tid+st]);
            rMx[tid]=fmaxf(rMx[tid],rMx[tid+st]);
        }
        __syncthreads();
    }
    if(tid==0){
        bpart[bl*8+0]=rS[0];
        bpart[bl*8+3]=rMn[0];
        bpart[bl*8+4]=rMx[0];
    }
}

// ---------------- k_resp: chp + 9x9 bank conv + csraw + top2 softmax ----------------
// grid 256: bl = b*32+band, band = 2 output rows; 2 threads/px x 4 protos
__global__ void __launch_bounds__(256) k_resp(const float* __restrict__ cm,
    const float* __restrict__ klg, const float* __restrict__ theta,
    const float* __restrict__ length, const float* __restrict__ width,
    const float* __restrict__ plog,
    float* __restrict__ csraw, float* __restrict__ ss0, float* __restrict__ bpart){
    __shared__ float cmT[768];       // rows y0-5..y0+6
    __shared__ float chpT[640];      // rows y0-4..y0+5
    __shared__ float klS[648];
    __shared__ float mg[128][8];
    __shared__ float rMn[256], rMx[256];
    int tid=threadIdx.x, bl=blockIdx.x;
    int b=bl>>5, band=bl&31, y0=band<<1;
    for(int i=tid;i<648;i+=256) klS[i]=klg[i];
    for(int j=tid;j<768;j+=256){
        int r=j>>6, x=j&63;
        int gy=y0-5+r;
        cmT[j]=(gy>=0&&gy<64)?cm[(b<<12)+(gy<<6)+x]:0.f;
    }
    __syncthreads();
    for(int j=tid;j<640;j+=256){
        int rh=j>>6, x=j&63;
        int gy=y0-4+rh;
        float v=0.f;
        if(gy>=0&&gy<64){
            float s=0.f;
            #pragma unroll
            for(int dy=-1;dy<=1;dy++){
                #pragma unroll
                for(int dx=-1;dx<=1;dx++){
                    int xx=x+dx;
                    if(xx>=0&&xx<64) s+=cmT[(rh+1+dy)*64+xx];
                }
            }
            v=cmT[(rh+1)*64+x]-s*(1.f/9.f);
        }
        chpT[j]=v;
    }
    __syncthreads();
    int px=tid&127, half=tid>>7;
    int ly=px>>6, x=px&63, gy=y0+ly;
    int gp=(b<<12)+(gy<<6)+x;
    float acc[4];
    #pragma unroll
    for(int qq=0;qq<4;qq++) acc[qq]=0.f;
    float cs=0.f;
    for(int dy=-4;dy<=4;dy++){
        int lr=ly+dy+4;
        for(int dx=-4;dx<=4;dx++){
            int xx=x+dx;
            float v=(xx>=0&&xx<64)?chpT[lr*64+xx]:0.f;
            int ti=(dy+4)*9+(dx+4);
            #pragma unroll
            for(int qq=0;qq<4;qq++) acc[qq]+=v*klS[(half*4+qq)*81+ti];
            if(half==0 && dy>=-1&&dy<=1&&dx>=-1&&dx<=1) cs+=fabsf(v);
        }
    }
    float ta=tanhf(theta[gp])*PI_F;
    float lv=sigm_f(length[gp])*0.85f+0.25f;
    float wv=sigm_f(width[gp])*0.22f+0.08f;
    const float Ls[3]={0.45f,0.75f,1.05f};
    const float Ws[3]={0.14f,0.20f,0.28f};
    int pp=(gy<<6)+x;
    float m1=-1e30f,m2=-1e30f,r1v=0.f,r2v=0.f;
    #pragma unroll
    for(int qq=0;qq<4;qq++){
        int q=half*4+qq;
        float ang=2.f*PI_F*(float)q*0.125f;
        float la=Ls[q%3], wa=Ws[(q/3)%3];
        float bias=plog[((size_t)((b<<3)+q)<<12)+pp]
                 +1.25f*cosf(ta-ang)
                 -(lv-la)*(lv-la)*(1.f/0.08f)
                 -(wv-wa)*(wv-wa)*(1.f/0.01f);
        if(bias>m1){m2=m1;r2v=r1v;m1=bias;r1v=acc[qq];}
        else if(bias>m2){m2=bias;r2v=acc[qq];}
    }
    mg[px][half*4+0]=m1; mg[px][half*4+1]=r1v;
    mg[px][half*4+2]=m2; mg[px][half*4+3]=r2v;
    __syncthreads();
    float cMn=1e30f, cMx=-1e30f;
    if(half==0){
        float m1a=mg[px][0], r1a=mg[px][1], m2a=mg[px][2], r2a=mg[px][3];
        float m1b=mg[px][4], r1b=mg[px][5], m2b=mg[px][6], r2b=mg[px][7];
        // merge two sorted top-2 lists; prefer lower-q (a) on ties, as in serial scan
        float M1,R1,M2,R2;
        if(m1b>m1a){ M1=m1b;R1=r1b; if(m2b>m1a){M2=m2b;R2=r2b;} else {M2=m1a;R2=r1a;} }
        else       { M1=m1a;R1=r1a; if(m1b>m2a){M2=m1b;R2=r1b;} else {M2=m2a;R2=r2a;} }
        float e2=expf(M2-M1);
        float inv=1.0f/(1.0f+e2);
        ss0[gp]=R1*inv + R2*e2*inv;
        float csv=cs*(1.f/9.f);
        csraw[gp]=csv;
        cMn=csv; cMx=csv;
    }
    rMn[tid]=cMn; rMx[tid]=cMx;
    __syncthreads();
    for(int st=128;st>0;st>>=1){
        if(tid<st){
            rMn[tid]=fminf(rMn[tid],rMn[tid+st]);
            rMx[tid]=fmaxf(rMx[tid],rMx[tid+st]);
        }
        __syncthreads();
    }
    if(tid==0){
        bpart[bl*8+1]=rMn[0];
        bpart[bl*8+2]=rMx[0];
    }
}

// ---------------- K3 (k_gate): partial-reduce + full gate pipeline in LDS ----------------
__global__ void __launch_bounds__(1024) k_gate(const float* __restrict__ csraw,
    const float* __restrict__ absc, const float* __restrict__ objn,
    const float* __restrict__ alpha, const float* __restrict__ bpart,
    float* __restrict__ sg){
    __shared__ float A[4096], Bs[4096], Cs[4096];
    __shared__ float red5[5];
    int b=blockIdx.x, tid=threadIdx.x;
    if(tid==0){
        float sm=0.f, cmn=1e30f, cmx=-1e30f, amn=1e30f, amx=-1e30f;
        for(int j=0;j<32;j++){
            const float* bp=&bpart[(b*32+j)*8];
            sm+=bp[0];
            cmn=fminf(cmn,bp[1]); cmx=fmaxf(cmx,bp[2]);
            amn=fminf(amn,bp[3]); amx=fmaxf(amx,bp[4]);
        }
        float den=fmaxf(sm*(1.0f/4096.0f),1e-6f);
        red5[0]=den; red5[1]=cmn; red5[2]=cmx; red5[3]=amn/den; red5[4]=amx/den;
    }
    __syncthreads();
    float den=red5[0], cmn=red5[1], cmx=red5[2], dmn=red5[3], dmx=red5[4];
    float cinv = 1.0f/fmaxf(cmx-cmn,1e-6f);
    float dinv = 1.0f/fmaxf(dmx-dmn,1e-6f);
    for(int k=0;k<4;k++){
        int p=tid+k*1024;
        float cs=(csraw[(b<<12)+p]-cmn)*cinv;
        float d = absc[(b<<12)+p]/den;
        float ds=(d-dmn)*dinv;
        float ev = 0.65f*cs + 0.35f*ds;
        A[p]=ev;
        Bs[p]=sigm_f((ev-0.2f)*(1.0f/0.08f));
    }
    __syncthreads();
    for(int k=0;k<4;k++){
        int p=tid+k*1024; int y=p>>6,x=p&63;
        float m=-1e30f;
        for(int dy=-2;dy<=2;dy++){int yy=y+dy; if(yy<0||yy>=64)continue;
            for(int dx=-2;dx<=2;dx++){int xx=x+dx; if(xx<0||xx>=64)continue;
                m=fmaxf(m,Bs[(yy<<6)+xx]);}}
        Cs[p]=m;
    }
    __syncthreads();
    for(int k=0;k<4;k++){
        int p=tid+k*1024; int y=p>>6,x=p&63;
        float m=1.f;
        for(int dy=-2;dy<=2;dy++){int yy=y+dy; if(yy<0||yy>=64)continue;
            for(int dx=-2;dx<=2;dx++){int xx=x+dx; if(xx<0||xx>=64)continue;
                if (A[(yy<<6)+xx] < 0.2f) m=0.f;}}
        Bs[p]=m;
    }
    __syncthreads();
    for(int k=0;k<4;k++){
        int p=tid+k*1024; int y=p>>6,x=p&63;
        float m=-1e30f;
        for(int dy=-2;dy<=2;dy++){int yy=y+dy; if(yy<0||yy>=64)continue;
            for(int dx=-2;dx<=2;dx++){int xx=x+dx; if(xx<0||xx>=64)continue;
                m=fmaxf(m,Bs[(yy<<6)+xx]);}}
        A[p]=m;
    }
    __syncthreads();
    for(int k=0;k<4;k++){
        int p=tid+k*1024; int y=p>>6,x=p&63;
        float m=-1e30f;
        for(int dy=-2;dy<=2;dy++){int yy=y+dy; if(yy<0||yy>=64)continue;
            for(int dx=-2;dx<=2;dx++){int xx=x+dx; if(xx<0||xx>=64)continue;
                m=fmaxf(m,A[(yy<<6)+xx]);}}
        Bs[p]=m;
    }
    __syncthreads();
    for(int k=0;k<4;k++){
        int p=tid+k*1024;
        A[p]=sigm_f(objn[(b<<12)+p]);
    }
    __syncthreads();
    for(int k=0;k<4;k++){
        int p=tid+k*1024; int y=p>>6,x=p&63;
        float s=0.f;
        for(int dy=-1;dy<=1;dy++){int yy=y+dy; if(yy<0||yy>=64)continue;
            for(int dx=-1;dx<=1;dx++){int xx=x+dx; if(xx<0||xx>=64)continue;
                s += A[(yy<<6)+xx];}}
        float blob = s*(1.0f/9.0f);
        float gate = Cs[p]*Bs[p];
        float d = absc[(b<<12)+p]/den;
        float sgv = sigm_f(alpha[(b<<12)+p]) * blob * gate * (0.7f+0.3f*fminf(fmaxf(d,0.f),2.f));
        sg[(b<<12)+p] = sgv;
    }
}

// ---------------- K4 (k_out): k_h + pm2 fused ----------------
// grid 256 x 256: block handles 32 f4px (128 px); phase1 h->LDS, phase2 8->768 expand
__global__ void __launch_bounds__(256) k_out(const float* __restrict__ ss0,
    const float* __restrict__ sg, const float* __restrict__ theta,
    const float* __restrict__ curv, const float* __restrict__ carrier,
    const float* __restrict__ w3, const float* __restrict__ b3,
    const float* __restrict__ w4, const float* __restrict__ b4,
    float* __restrict__ out){
    __shared__ float hS[8][128];     // 4 KB
    __shared__ float w4s[768*8];     // 24 KB
    __shared__ float b4s[768];
    __shared__ float wl[96];
    __shared__ float bl3[8];
    int tid=threadIdx.x;
    int bln=blockIdx.x;
    for(int i=tid;i<6144;i+=256) w4s[i]=w4[i];
    for(int i=tid;i<768;i+=256) b4s[i]=b4[i];
    if(tid<96) wl[tid]=w3[tid];
    if(tid<8) bl3[tid]=b3[tid];
    __syncthreads();   // wl/bl3 written by waves 0-1, read cross-wave below

    if(tid<128){
        int gp=bln*128+tid;
        int b=gp>>12, p=gp&4095, y=p>>6, x=p&63;
        const float* base = ss0 + (b<<12);
        float s=0.f;
        for(int dy=-1;dy<=1;dy++){int yy=y+dy; if(yy<0||yy>=64)continue;
            for(int dx=-1;dx<=1;dx++){int xx=x+dx;if(xx<0||xx>=64)continue;
                s+=base[(yy<<6)+xx];}}
        float ss1 = base[p]-s*(1.0f/9.0f);
        float cu = tanhf(curv[gp]);
        float ssv = sg[gp]*ss1*(1.0f+0.15f*cu);
        float ta = tanhf(theta[gp])*PI_F;
        float dxv=cosf(ta), dyv=sinf(ta);
        float car[8];
        #pragma unroll
        for(int ci=0;ci<8;ci++) car[ci]=carrier[((size_t)((b<<3)+ci)<<12)+p];
        #pragma unroll
        for(int co=0;co<8;co++){
            const float* w=&wl[co*12];
            float t = w[8] + w[9]*dxv + w[10]*dyv + w[11]*cu;
            #pragma unroll
            for(int ci=0;ci<8;ci++) t += w[ci]*car[ci];
            hS[co][tid] = gelu_f(bl3[co] + ssv*t);
        }
    }
    __syncthreads();

    int px4 = tid&31;          // f4 px within block
    int cg = tid>>5;           // 0..7, 96 co each
    int q0 = bln*32 + px4;     // GLOBAL f4 index (0..8191)
    int b = q0>>10;
    int ql = q0 & 1023;        // within-batch f4 index
    float4 hv[8];
    #pragma unroll
    for(int ci=0;ci<8;ci++) hv[ci]=*(const float4*)&hS[ci][px4<<2];
    float4* o4=(float4*)out;
    for(int k=0;k<96;k++){
        int co=cg*96+k;
        float bb=b4s[co];
        float4 o=make_float4(bb,bb,bb,bb);
        const float* w=&w4s[co<<3];
        #pragma unroll
        for(int ci=0;ci<8;ci++){
            float wv=w[ci];
            o.x+=wv*hv[ci].x; o.y+=wv*hv[ci].y; o.z+=wv*hv[ci].z; o.w+=wv*hv[ci].w;
        }
        o4[(size_t)(b*768+co)*1024 + ql]=o;
    }
}

extern "C" void kernel_launch(void* const* d_in, const int* in_sizes, int n_in,
                              void* d_out, int out_size, void* d_ws, size_t ws_size,
                              hipStream_t stream) {
    const float* fm     =(const float*)d_in[0];
    const float* theta  =(const float*)d_in[1];
    const float* length =(const float*)d_in[2];
    const float* width  =(const float*)d_in[3];
    const float* curv   =(const float*)d_in[4];
    const float* alpha  =(const float*)d_in[5];
    const float* objn   =(const float*)d_in[6];
    const float* plog   =(const float*)d_in[7];
    const float* fp1w   =(const float*)d_in[8];
    const float* fp1b   =(const float*)d_in[9];
    const float* fp2w   =(const float*)d_in[10];
    const float* fp2b   =(const float*)d_in[11];
    const float* pm1w   =(const float*)d_in[12];
    const float* pm1b   =(const float*)d_in[13];
    const float* pm2w   =(const float*)d_in[14];
    const float* pm2b   =(const float*)d_in[15];
    const float* pdelta =(const float*)d_in[16];

    float* ws=(float*)d_ws;
    float* part    = ws;                  // 8*8*32768 = 2097152
    float* t1      = part;                // alias: g=0 planes after k_comb (8*32768)
    float* cm      = part + 262144;       // alias: g=1 plane region, 32768 used
    float* carrier = part + 2097152;      // 262144
    float* absc    = carrier + 262144;    // 32768
    float* csraw   = absc + 32768;        // 32768
    float* ss0     = csraw + 32768;       // 32768
    float* sg      = ss0 + 32768;         // 32768
    float* bpart   = sg + 32768;          // 2048
    float* klg     = bpart + 2048;        // 648
    float* out     = (float*)d_out;

    k_bank <<<1, 256, 0, stream>>>(pdelta, klg);
    k_conv1<<<dim3(32,8), 256, 0, stream>>>(fm, fp1w, part);
    k_comb <<<256, 256, 0, stream>>>(part, fp1b);
    k_conv2<<<256, 256, 0, stream>>>(t1, fp2w, fp2b, carrier, cm, absc, bpart);
    k_resp <<<256, 256, 0, stream>>>(cm, klg, theta, length, width, plog,
                                     csraw, ss0, bpart);
    k_gate <<<8, 1024, 0, stream>>>(csraw, absc, objn, alpha, bpart, sg);
    k_out  <<<256, 256, 0, stream>>>(ss0, sg, theta, curv, carrier,
                                     pm1w, pm1b, pm2w, pm2b, out);
}

// Round 3
// 299.250 us; speedup vs baseline: 1.1724x; 1.0256x over previous
//
#include <hip/hip_runtime.h>
#include <math.h>

#define PI_F 3.14159265358979323846f

__device__ __forceinline__ float gelu_f(float x){ return 0.5f*x*(1.0f+erff(x*0.7071067811865475f)); }
__device__ __forceinline__ float sigm_f(float x){ return 1.0f/(1.0f+expf(-x)); }

// B=8, H=W=64, HW=4096, NP=32768, FC=768, RC=8, P=8, K=9, G=8 channel groups

// ---------------- K1: fp1 1x1 conv 768->8, channel-split partials + bank fold ----------------
// grid (64,8): chunk = b*8+sub (128 f4 each), g = channel group (96 ch)
__global__ void __launch_bounds__(256) k_conv1(const float* __restrict__ fm,
                        const float* __restrict__ w1, const float* __restrict__ pd,
                        float* __restrict__ part, float* __restrict__ klg){
    int chunk = blockIdx.x;   // 0..63
    int g = blockIdx.y;       // 0..7
    int tid = threadIdx.x;
    __shared__ float wl[96*8];
    __shared__ float4 comb[8][128];   // 16 KB
    for (int i=tid;i<768;i+=256){ int c=i>>3, co=i&7; wl[i]=w1[co*768 + g*96 + c]; }
    __syncthreads();
    int b = chunk>>3;
    int f4 = tid&127, half = tid>>7;
    int q0 = ((chunk&7)<<7) + f4;   // f4 offset within batch plane (0..1023)
    const float4* fm4 = (const float4*)fm;
    float4 acc[8];
    #pragma unroll
    for(int co=0;co<8;co++) acc[co]=make_float4(0.f,0.f,0.f,0.f);
    int basec = b*768 + g*96 + half*48;
    for(int c=0;c<48;c++){
        float4 x = fm4[(size_t)(basec+c)*1024 + q0];
        int ch = half*48 + c;
        #pragma unroll
        for(int co=0;co<8;co++){
            float wv = wl[(ch<<3)+co];
            acc[co].x += wv*x.x; acc[co].y += wv*x.y; acc[co].z += wv*x.z; acc[co].w += wv*x.w;
        }
    }
    if(half==1){
        #pragma unroll
        for(int co=0;co<8;co++) comb[co][f4]=acc[co];
    }
    __syncthreads();
    if(half==0){
        float4* p4 = (float4*)part;
        int gq = (b<<10) + q0;
        #pragma unroll
        for(int co=0;co<8;co++){
            float4 o = comb[co][f4];
            o.x+=acc[co].x; o.y+=acc[co].y; o.z+=acc[co].z; o.w+=acc[co].w;
            p4[(size_t)((g<<3)+co)*8192 + gq] = o;
        }
    }

    // ---- bank build (one block only) ----
    if(chunk==0 && g==0){
        __shared__ float ridge[648];
        __shared__ float pmS[8], pdenS[8];
        for(int t=tid;t<648;t+=256){
            int p=t/81, idx=t-p*81;
            int i=idx/9, j=idx-i*9;
            float ay=-1.f+0.25f*(float)i;
            float ax=-1.f+0.25f*(float)j;
            float ang=2.f*PI_F*(float)p*0.125f;
            const float Ls[3]={0.45f,0.75f,1.05f};
            const float Ws[3]={0.14f,0.20f,0.28f};
            float L=Ls[p%3], Wd=Ws[(p/3)%3];
            float cs=cosf(ang), sn=sinf(ang);
            float xr=ax*cs+ay*sn;
            float yr=-ax*sn+ay*cs;
            float tp=1.f-fminf(fabsf(xr)/L,1.f);
            float taper=powf(tp,1.5f);
            float core=expf(-0.5f*((xr/L)*(xr/L)+(yr/Wd)*(yr/Wd)));
            ridge[t]=taper*core*fmaxf(1.f-(yr/Wd)*(yr/Wd),0.f);
        }
        __syncthreads();
        {
            int p=tid>>5, k=tid&31;
            float s=0.f;
            for(int e=k;e<81;e+=32) s+=ridge[p*81+e];
            for(int off=16;off>0;off>>=1) s+=__shfl_down(s,off,32);
            if(k==0) pmS[p]=s*(1.f/81.f);
        }
        __syncthreads();
        {
            int p=tid>>5, k=tid&31;
            float m=pmS[p];
            float s=0.f;
            for(int e=k;e<81;e+=32) s+=fabsf(ridge[p*81+e]-m);
            for(int off=16;off>0;off>>=1) s+=__shfl_down(s,off,32);
            if(k==0) pdenS[p]=fmaxf(s,1e-6f);
        }
        __syncthreads();
        for(int t=tid;t<648;t+=256){
            int p=t/81;
            klg[t]=(ridge[t]-pmS[p])/pdenS[p]+0.05f*pd[t];
        }
    }
}

// ---------------- k_conv2: partial-sum + gelu + 3x3 conv 8->8 -> carrier, cm, absc ----------------
// grid 256: bl = b*32+band, band = 2 output rows
__global__ void __launch_bounds__(256) k_conv2(const float* __restrict__ part,
    const float* __restrict__ b1, const float* __restrict__ w2, const float* __restrict__ b2,
    float* __restrict__ carrier, float* __restrict__ cm, float* __restrict__ absc,
    float* __restrict__ bpart){
    __shared__ float t1T[8][256];    // rows y0-1..y0+2
    __shared__ float w2s[576];
    __shared__ float b1s[8];
    __shared__ float sumS[2][128];
    __shared__ float saS[2][128];
    __shared__ float rS[256], rMn[256], rMx[256];
    int tid=threadIdx.x, bl=blockIdx.x;
    int b=bl>>5, band=bl&31, y0=band<<1;
    for(int i=tid;i<576;i+=256) w2s[i]=w2[i];
    if(tid<8) b1s[tid]=b1[tid];
    __syncthreads();
    for(int j=tid;j<2048;j+=256){
        int co=j>>8, pos=j&255, r=pos>>6, x=pos&63;
        int gy=y0-1+r;
        float v=0.f;
        if(gy>=0 && gy<64){
            int px=(b<<12)+(gy<<6)+x;
            float s=0.f;
            #pragma unroll
            for(int g=0;g<8;g++) s+=part[(size_t)((g<<3)+co)*32768+px];
            v=gelu_f(s+b1s[co]);
        }
        t1T[co][pos]=v;
    }
    __syncthreads();
    int px=tid&127, half=tid>>7;
    int ly=px>>6, x=px&63, gy=y0+ly;
    float acc[4];
    #pragma unroll
    for(int qq=0;qq<4;qq++) acc[qq]=b2[half*4+qq];
    for(int ci=0;ci<8;ci++){
        #pragma unroll
        for(int dy=-1;dy<=1;dy++){
            int tr=ly+1+dy;
            #pragma unroll
            for(int dx=-1;dx<=1;dx++){
                int xx=x+dx;
                float v=(xx>=0&&xx<64)?t1T[ci][tr*64+xx]:0.f;
                int ti=(dy+1)*3+(dx+1);
                #pragma unroll
                for(int qq=0;qq<4;qq++) acc[qq]+=v*w2s[((half*4+qq)*8+ci)*9+ti];
            }
        }
    }
    float s4=0.f, sa4=0.f;
    #pragma unroll
    for(int qq=0;qq<4;qq++){
        float cv=gelu_f(acc[qq]);
        carrier[((size_t)((b<<3)+half*4+qq)<<12)+(gy<<6)+x]=cv;
        s4+=cv; sa4+=fabsf(cv);
    }
    sumS[half][px]=s4; saS[half][px]=sa4;
    __syncthreads();
    float aS=0.f, aMn=1e30f, aMx=-1e30f;
    if(half==0){
        float cmv=(sumS[0][px]+sumS[1][px])*0.125f;
        float av =(saS[0][px]+saS[1][px])*0.125f;
        int gp=(b<<12)+(gy<<6)+x;
        cm[gp]=cmv;
        absc[gp]=av;
        aS=av; aMn=av; aMx=av;
    }
    rS[tid]=aS; rMn[tid]=aMn; rMx[tid]=aMx;
    __syncthreads();
    for(int st=128;st>0;st>>=1){
        if(tid<st){
            rS[tid]+=rS[tid+st];
            rMn[tid]=fminf(rMn[tid],rMn[tid+st]);
            rMx[tid]=fmaxf(rMx[tid],rMx[tid+st]);
        }
        __syncthreads();
    }
    if(tid==0){
        bpart[bl*8+0]=rS[0];
        bpart[bl*8+3]=rMn[0];
        bpart[bl*8+4]=rMx[0];
    }
}

// ---------------- k_resp: chp + 9x9 bank conv + csraw + top2 softmax ----------------
// grid 256: bl = b*32+band, band = 2 output rows; 2 threads/px x 4 protos
__global__ void __launch_bounds__(256) k_resp(const float* __restrict__ cm,
    const float* __restrict__ klg, const float* __restrict__ theta,
    const float* __restrict__ length, const float* __restrict__ width,
    const float* __restrict__ plog,
    float* __restrict__ csraw, float* __restrict__ ss0, float* __restrict__ bpart){
    __shared__ float cmT[768];       // rows y0-5..y0+6
    __shared__ float chpT[640];      // rows y0-4..y0+5
    __shared__ float klS[648];
    __shared__ float mg[128][8];
    __shared__ float rMn[256], rMx[256];
    int tid=threadIdx.x, bl=blockIdx.x;
    int b=bl>>5, band=bl&31, y0=band<<1;
    for(int i=tid;i<648;i+=256) klS[i]=klg[i];
    for(int j=tid;j<768;j+=256){
        int r=j>>6, x=j&63;
        int gy=y0-5+r;
        cmT[j]=(gy>=0&&gy<64)?cm[(b<<12)+(gy<<6)+x]:0.f;
    }
    __syncthreads();
    for(int j=tid;j<640;j+=256){
        int rh=j>>6, x=j&63;
        int gy=y0-4+rh;
        float v=0.f;
        if(gy>=0&&gy<64){
            float s=0.f;
            #pragma unroll
            for(int dy=-1;dy<=1;dy++){
                #pragma unroll
                for(int dx=-1;dx<=1;dx++){
                    int xx=x+dx;
                    if(xx>=0&&xx<64) s+=cmT[(rh+1+dy)*64+xx];
                }
            }
            v=cmT[(rh+1)*64+x]-s*(1.f/9.f);
        }
        chpT[j]=v;
    }
    __syncthreads();
    int px=tid&127, half=tid>>7;
    int ly=px>>6, x=px&63, gy=y0+ly;
    int gp=(b<<12)+(gy<<6)+x;
    float acc[4];
    #pragma unroll
    for(int qq=0;qq<4;qq++) acc[qq]=0.f;
    float cs=0.f;
    for(int dy=-4;dy<=4;dy++){
        int lr=ly+dy+4;
        for(int dx=-4;dx<=4;dx++){
            int xx=x+dx;
            float v=(xx>=0&&xx<64)?chpT[lr*64+xx]:0.f;
            int ti=(dy+4)*9+(dx+4);
            #pragma unroll
            for(int qq=0;qq<4;qq++) acc[qq]+=v*klS[(half*4+qq)*81+ti];
            if(half==0 && dy>=-1&&dy<=1&&dx>=-1&&dx<=1) cs+=fabsf(v);
        }
    }
    float ta=tanhf(theta[gp])*PI_F;
    float lv=sigm_f(length[gp])*0.85f+0.25f;
    float wv=sigm_f(width[gp])*0.22f+0.08f;
    const float Ls[3]={0.45f,0.75f,1.05f};
    const float Ws[3]={0.14f,0.20f,0.28f};
    int pp=(gy<<6)+x;
    float m1=-1e30f,m2=-1e30f,r1v=0.f,r2v=0.f;
    #pragma unroll
    for(int qq=0;qq<4;qq++){
        int q=half*4+qq;
        float ang=2.f*PI_F*(float)q*0.125f;
        float la=Ls[q%3], wa=Ws[(q/3)%3];
        float bias=plog[((size_t)((b<<3)+q)<<12)+pp]
                 +1.25f*cosf(ta-ang)
                 -(lv-la)*(lv-la)*(1.f/0.08f)
                 -(wv-wa)*(wv-wa)*(1.f/0.01f);
        if(bias>m1){m2=m1;r2v=r1v;m1=bias;r1v=acc[qq];}
        else if(bias>m2){m2=bias;r2v=acc[qq];}
    }
    mg[px][half*4+0]=m1; mg[px][half*4+1]=r1v;
    mg[px][half*4+2]=m2; mg[px][half*4+3]=r2v;
    __syncthreads();
    float cMn=1e30f, cMx=-1e30f;
    if(half==0){
        float m1a=mg[px][0], r1a=mg[px][1], m2a=mg[px][2], r2a=mg[px][3];
        float m1b=mg[px][4], r1b=mg[px][5], m2b=mg[px][6], r2b=mg[px][7];
        float M1,R1,M2,R2;
        if(m1b>m1a){ M1=m1b;R1=r1b; if(m2b>m1a){M2=m2b;R2=r2b;} else {M2=m1a;R2=r1a;} }
        else       { M1=m1a;R1=r1a; if(m1b>m2a){M2=m1b;R2=r1b;} else {M2=m2a;R2=r2a;} }
        float e2=expf(M2-M1);
        float inv=1.0f/(1.0f+e2);
        ss0[gp]=R1*inv + R2*e2*inv;
        float csv=cs*(1.f/9.f);
        csraw[gp]=csv;
        cMn=csv; cMx=csv;
    }
    rMn[tid]=cMn; rMx[tid]=cMx;
    __syncthreads();
    for(int st=128;st>0;st>>=1){
        if(tid<st){
            rMn[tid]=fminf(rMn[tid],rMn[tid+st]);
            rMx[tid]=fmaxf(rMx[tid],rMx[tid+st]);
        }
        __syncthreads();
    }
    if(tid==0){
        bpart[bl*8+1]=rMn[0];
        bpart[bl*8+2]=rMx[0];
    }
}

// ---------------- k_gate: tiled gate pipeline, 64 blocks (8 segments/batch) ----------------
__global__ void __launch_bounds__(256) k_gate(const float* __restrict__ csraw,
    const float* __restrict__ absc, const float* __restrict__ objn,
    const float* __restrict__ alpha, const float* __restrict__ bpart,
    float* __restrict__ sg){
    __shared__ float evT[1280];   // rows y0-6 .. y0+13
    __shared__ float gmT[1280];   // sigm gate, same rows
    __shared__ float eT[1024];    // erode, rows y0-4 .. y0+11
    __shared__ float m1T[768];    // dilate, rows y0-2 .. y0+9
    __shared__ float obT[640];    // sigm(objn), rows y0-1 .. y0+8
    __shared__ float red5[5];
    int blk=blockIdx.x, tid=threadIdx.x;
    int b=blk>>3, y0=(blk&7)<<3;
    if(tid==0){
        float sm=0.f, cmn=1e30f, cmx=-1e30f, amn=1e30f, amx=-1e30f;
        for(int j=0;j<32;j++){
            const float* bp=&bpart[(b*32+j)*8];
            sm+=bp[0];
            cmn=fminf(cmn,bp[1]); cmx=fmaxf(cmx,bp[2]);
            amn=fminf(amn,bp[3]); amx=fmaxf(amx,bp[4]);
        }
        float den=fmaxf(sm*(1.0f/4096.0f),1e-6f);
        red5[0]=den; red5[1]=cmn; red5[2]=cmx; red5[3]=amn/den; red5[4]=amx/den;
    }
    __syncthreads();
    float den=red5[0], cmn=red5[1], dmn=red5[3];
    float cinv = 1.0f/fmaxf(red5[2]-cmn,1e-6f);
    float dinv = 1.0f/fmaxf(red5[4]-dmn,1e-6f);
    for(int j=tid;j<1280;j+=256){
        int r=j>>6, x=j&63; int gy=y0-6+r;
        float ev=0.f;
        if(gy>=0&&gy<64){
            int gp=(b<<12)+(gy<<6)+x;
            float cs=(csraw[gp]-cmn)*cinv;
            float d=absc[gp]/den;
            ev=0.65f*cs+0.35f*((d-dmn)*dinv);
        }
        evT[j]=ev;
        gmT[j]=sigm_f((ev-0.2f)*(1.0f/0.08f));
    }
    for(int j=tid;j<640;j+=256){
        int r=j>>6,x=j&63; int gy=y0-1+r;
        obT[j]=(gy>=0&&gy<64)?sigm_f(objn[(b<<12)+(gy<<6)+x]):0.f;
    }
    __syncthreads();
    // erode: mask=ev>=THR; e=1 iff all valid 5x5 neighbors have mask==1
    for(int j=tid;j<1024;j+=256){
        int r=j>>6,x=j&63; int gy=y0-4+r;
        float m=0.f;
        if(gy>=0&&gy<64){
            m=1.f;
            for(int dy=-2;dy<=2;dy++){int yy=gy+dy; if(yy<0||yy>=64)continue;
                int lr=yy-(y0-6);
                for(int dx=-2;dx<=2;dx++){int xx=x+dx; if(xx<0||xx>=64)continue;
                    if(evT[(lr<<6)+xx]<0.2f) m=0.f;}}
        }
        eT[j]=m;
    }
    __syncthreads();
    // dilate e -> m1
    for(int j=tid;j<768;j+=256){
        int r=j>>6,x=j&63; int gy=y0-2+r;
        float m=0.f;
        if(gy>=0&&gy<64){
            m=-1e30f;
            for(int dy=-2;dy<=2;dy++){int yy=gy+dy; if(yy<0||yy>=64)continue;
                int lr=yy-(y0-4);
                for(int dx=-2;dx<=2;dx++){int xx=x+dx; if(xx<0||xx>=64)continue;
                    m=fmaxf(m,eT[(lr<<6)+xx]);}}
        }
        m1T[j]=m;
    }
    __syncthreads();
    // final 512 px
    for(int k=0;k<2;k++){
        int p=tid+(k<<8);
        int ly=p>>6, x=p&63; int gy=y0+ly;
        int gp=(b<<12)+(gy<<6)+x;
        float m2=-1e30f, gx=-1e30f;
        for(int dy=-2;dy<=2;dy++){int yy=gy+dy; if(yy<0||yy>=64)continue;
            int lr1=yy-(y0-2), lr2=yy-(y0-6);
            for(int dx=-2;dx<=2;dx++){int xx=x+dx; if(xx<0||xx>=64)continue;
                m2=fmaxf(m2,m1T[(lr1<<6)+xx]);
                gx=fmaxf(gx,gmT[(lr2<<6)+xx]);}}
        float s=0.f;
        for(int dy=-1;dy<=1;dy++){int yy=gy+dy; if(yy<0||yy>=64)continue;
            int lr=yy-(y0-1);
            for(int dx=-1;dx<=1;dx++){int xx=x+dx; if(xx<0||xx>=64)continue;
                s+=obT[(lr<<6)+xx];}}
        float blob=s*(1.0f/9.0f);
        float gate=gx*m2;
        float d=absc[gp]/den;
        sg[gp]=sigm_f(alpha[gp])*blob*gate*(0.7f+0.3f*fminf(fmaxf(d,0.f),2.f));
    }
}

// ---------------- k_out: h + pm2 fused, 512 blocks of 16 f4 px ----------------
__global__ void __launch_bounds__(256) k_out(const float* __restrict__ ss0,
    const float* __restrict__ sg, const float* __restrict__ theta,
    const float* __restrict__ curv, const float* __restrict__ carrier,
    const float* __restrict__ w3, const float* __restrict__ b3,
    const float* __restrict__ w4, const float* __restrict__ b4,
    float* __restrict__ out){
    __shared__ float hS[8][64];      // 2 KB
    __shared__ float w4s[768*8];     // 24 KB
    __shared__ float b4s[768];
    __shared__ float wl[96];
    __shared__ float bl3[8];
    int tid=threadIdx.x;
    int bln=blockIdx.x;              // 0..511
    for(int i=tid;i<6144;i+=256) w4s[i]=w4[i];
    for(int i=tid;i<768;i+=256) b4s[i]=b4[i];
    if(tid<96) wl[tid]=w3[tid];
    if(tid<8) bl3[tid]=b3[tid];
    __syncthreads();

    if(tid<64){
        int gp=bln*64+tid;
        int b=gp>>12, p=gp&4095, y=p>>6, x=p&63;
        const float* base = ss0 + (b<<12);
        float s=0.f;
        for(int dy=-1;dy<=1;dy++){int yy=y+dy; if(yy<0||yy>=64)continue;
            for(int dx=-1;dx<=1;dx++){int xx=x+dx;if(xx<0||xx>=64)continue;
                s+=base[(yy<<6)+xx];}}
        float ss1 = base[p]-s*(1.0f/9.0f);
        float cu = tanhf(curv[gp]);
        float ssv = sg[gp]*ss1*(1.0f+0.15f*cu);
        float ta = tanhf(theta[gp])*PI_F;
        float dxv=cosf(ta), dyv=sinf(ta);
        float car[8];
        #pragma unroll
        for(int ci=0;ci<8;ci++) car[ci]=carrier[((size_t)((b<<3)+ci)<<12)+p];
        #pragma unroll
        for(int co=0;co<8;co++){
            const float* w=&wl[co*12];
            float t = w[8] + w[9]*dxv + w[10]*dyv + w[11]*cu;
            #pragma unroll
            for(int ci=0;ci<8;ci++) t += w[ci]*car[ci];
            hS[co][tid] = gelu_f(bl3[co] + ssv*t);
        }
    }
    __syncthreads();

    int px4 = tid&15;          // f4 px within block
    int cg = tid>>4;           // 0..15, 48 co each
    int q0 = bln*16 + px4;     // GLOBAL f4 index (0..8191)
    int b = q0>>10;
    int ql = q0 & 1023;        // within-batch f4 index
    float4 hv[8];
    #pragma unroll
    for(int ci=0;ci<8;ci++) hv[ci]=*(const float4*)&hS[ci][px4<<2];
    float4* o4=(float4*)out;
    for(int k=0;k<48;k++){
        int co=cg*48+k;
        float bb=b4s[co];
        float4 o=make_float4(bb,bb,bb,bb);
        const float* w=&w4s[co<<3];
        #pragma unroll
        for(int ci=0;ci<8;ci++){
            float wv=w[ci];
            o.x+=wv*hv[ci].x; o.y+=wv*hv[ci].y; o.z+=wv*hv[ci].z; o.w+=wv*hv[ci].w;
        }
        o4[(size_t)(b*768+co)*1024 + ql]=o;
    }
}

extern "C" void kernel_launch(void* const* d_in, const int* in_sizes, int n_in,
                              void* d_out, int out_size, void* d_ws, size_t ws_size,
                              hipStream_t stream) {
    const float* fm     =(const float*)d_in[0];
    const float* theta  =(const float*)d_in[1];
    const float* length =(const float*)d_in[2];
    const float* width  =(const float*)d_in[3];
    const float* curv   =(const float*)d_in[4];
    const float* alpha  =(const float*)d_in[5];
    const float* objn   =(const float*)d_in[6];
    const float* plog   =(const float*)d_in[7];
    const float* fp1w   =(const float*)d_in[8];
    const float* fp1b   =(const float*)d_in[9];
    const float* fp2w   =(const float*)d_in[10];
    const float* fp2b   =(const float*)d_in[11];
    const float* pm1w   =(const float*)d_in[12];
    const float* pm1b   =(const float*)d_in[13];
    const float* pm2w   =(const float*)d_in[14];
    const float* pm2b   =(const float*)d_in[15];
    const float* pdelta =(const float*)d_in[16];

    float* ws=(float*)d_ws;
    float* part    = ws;                  // 8*8*32768 = 2097152 (all planes live)
    float* carrier = part + 2097152;      // 262144
    float* absc    = carrier + 262144;    // 32768
    float* csraw   = absc + 32768;        // 32768
    float* ss0     = csraw + 32768;       // 32768
    float* sg      = ss0 + 32768;         // 32768
    float* cm      = sg + 32768;          // 32768
    float* bpart   = cm + 32768;          // 2048
    float* klg     = bpart + 2048;        // 648
    float* out     = (float*)d_out;

    k_conv1<<<dim3(64,8), 256, 0, stream>>>(fm, fp1w, pdelta, part, klg);
    k_conv2<<<256, 256, 0, stream>>>(part, fp1b, fp2w, fp2b, carrier, cm, absc, bpart);
    k_resp <<<256, 256, 0, stream>>>(cm, klg, theta, length, width, plog,
                                     csraw, ss0, bpart);
    k_gate <<<64, 256, 0, stream>>>(csraw, absc, objn, alpha, bpart, sg);
    k_out  <<<512, 256, 0, stream>>>(ss0, sg, theta, curv, carrier,
                                     pm1w, pm1b, pm2w, pm2b, out);
}

// Round 6
// 284.500 us; speedup vs baseline: 1.2331x; 1.0518x over previous
//
#include <hip/hip_runtime.h>
#include <math.h>

#define PI_F 3.14159265358979323846f

__device__ __forceinline__ float gelu_f(float x){ return 0.5f*x*(1.0f+erff(x*0.7071067811865475f)); }
__device__ __forceinline__ float sigm_f(float x){ return 1.0f/(1.0f+expf(-x)); }

// native vector type for nontemporal builtins (HIP_vector_type is rejected by the builtin)
typedef float nf4 __attribute__((ext_vector_type(4)));
__device__ __forceinline__ float4 nt_load4(const float4* p){
    nf4 v = __builtin_nontemporal_load((const nf4*)p);
    return make_float4(v.x, v.y, v.z, v.w);
}
__device__ __forceinline__ void nt_store4(float4* p, float4 v){
    nf4 w; w.x=v.x; w.y=v.y; w.z=v.z; w.w=v.w;
    __builtin_nontemporal_store(w, (nf4*)p);
}

// B=8, H=W=64, HW=4096, NP=32768, FC=768, RC=8, P=8, K=9, G=8 channel groups

// ---------------- K1: fp1 1x1 conv 768->8, channel-split partials + bank fold ----------------
// grid (64,8): chunk = b*8+sub (128 f4 each), g = channel group (96 ch)
__global__ void __launch_bounds__(256) k_conv1(const float* __restrict__ fm,
                        const float* __restrict__ w1, const float* __restrict__ pd,
                        float* __restrict__ part, float* __restrict__ klg){
    int chunk = blockIdx.x;   // 0..63
    int g = blockIdx.y;       // 0..7
    int tid = threadIdx.x;
    __shared__ float wl[96*8];
    __shared__ float4 comb[8][128];   // 16 KB
    for (int i=tid;i<768;i+=256){ int c=i>>3, co=i&7; wl[i]=w1[co*768 + g*96 + c]; }
    __syncthreads();
    int b = chunk>>3;
    int f4 = tid&127, half = tid>>7;
    int q0 = ((chunk&7)<<7) + f4;   // f4 offset within batch plane (0..1023)
    const float4* fm4 = (const float4*)fm;
    float4 acc[8];
    #pragma unroll
    for(int co=0;co<8;co++) acc[co]=make_float4(0.f,0.f,0.f,0.f);
    int basec = b*768 + g*96 + half*48;
    for(int c=0;c<48;c++){
        float4 x = nt_load4(&fm4[(size_t)(basec+c)*1024 + q0]);
        int ch = half*48 + c;
        #pragma unroll
        for(int co=0;co<8;co++){
            float wv = wl[(ch<<3)+co];
            acc[co].x += wv*x.x; acc[co].y += wv*x.y; acc[co].z += wv*x.z; acc[co].w += wv*x.w;
        }
    }
    if(half==1){
        #pragma unroll
        for(int co=0;co<8;co++) comb[co][f4]=acc[co];
    }
    __syncthreads();
    if(half==0){
        float4* p4 = (float4*)part;
        int gq = (b<<10) + q0;
        #pragma unroll
        for(int co=0;co<8;co++){
            float4 o = comb[co][f4];
            o.x+=acc[co].x; o.y+=acc[co].y; o.z+=acc[co].z; o.w+=acc[co].w;
            p4[(size_t)((g<<3)+co)*8192 + gq] = o;
        }
    }

    // ---- bank build (one block only) ----
    if(chunk==0 && g==0){
        __shared__ float ridge[648];
        __shared__ float pmS[8], pdenS[8];
        for(int t=tid;t<648;t+=256){
            int p=t/81, idx=t-p*81;
            int i=idx/9, j=idx-i*9;
            float ay=-1.f+0.25f*(float)i;
            float ax=-1.f+0.25f*(float)j;
            float ang=2.f*PI_F*(float)p*0.125f;
            const float Ls[3]={0.45f,0.75f,1.05f};
            const float Ws[3]={0.14f,0.20f,0.28f};
            float L=Ls[p%3], Wd=Ws[(p/3)%3];
            float cs=cosf(ang), sn=sinf(ang);
            float xr=ax*cs+ay*sn;
            float yr=-ax*sn+ay*cs;
            float tp=1.f-fminf(fabsf(xr)/L,1.f);
            float taper=powf(tp,1.5f);
            float core=expf(-0.5f*((xr/L)*(xr/L)+(yr/Wd)*(yr/Wd)));
            ridge[t]=taper*core*fmaxf(1.f-(yr/Wd)*(yr/Wd),0.f);
        }
        __syncthreads();
        {
            int p=tid>>5, k=tid&31;
            float s=0.f;
            for(int e=k;e<81;e+=32) s+=ridge[p*81+e];
            for(int off=16;off>0;off>>=1) s+=__shfl_down(s,off,32);
            if(k==0) pmS[p]=s*(1.f/81.f);
        }
        __syncthreads();
        {
            int p=tid>>5, k=tid&31;
            float m=pmS[p];
            float s=0.f;
            for(int e=k;e<81;e+=32) s+=fabsf(ridge[p*81+e]-m);
            for(int off=16;off>0;off>>=1) s+=__shfl_down(s,off,32);
            if(k==0) pdenS[p]=fmaxf(s,1e-6f);
        }
        __syncthreads();
        for(int t=tid;t<648;t+=256){
            int p=t/81;
            klg[t]=(ridge[t]-pmS[p])/pdenS[p]+0.05f*pd[t];
        }
    }
}

// ---------------- k_conv2: partial-sum + gelu + 3x3 conv 8->8 -> carrier, cm, absc ----------------
// grid 256: bl = b*32+band, band = 2 output rows
__global__ void __launch_bounds__(256) k_conv2(const float* __restrict__ part,
    const float* __restrict__ b1, const float* __restrict__ w2, const float* __restrict__ b2,
    float* __restrict__ carrier, float* __restrict__ cm, float* __restrict__ absc,
    float* __restrict__ bpart){
    __shared__ float t1T[8][256];    // rows y0-1..y0+2
    __shared__ float w2s[576];
    __shared__ float b1s[8];
    __shared__ float sumS[2][128];
    __shared__ float saS[2][128];
    __shared__ float rS[256], rMn[256], rMx[256];
    int tid=threadIdx.x, bl=blockIdx.x;
    int b=bl>>5, band=bl&31, y0=band<<1;
    for(int i=tid;i<576;i+=256) w2s[i]=w2[i];
    if(tid<8) b1s[tid]=b1[tid];
    __syncthreads();
    for(int j=tid;j<2048;j+=256){
        int co=j>>8, pos=j&255, r=pos>>6, x=pos&63;
        int gy=y0-1+r;
        float v=0.f;
        if(gy>=0 && gy<64){
            int px=(b<<12)+(gy<<6)+x;
            float s=0.f;
            #pragma unroll
            for(int g=0;g<8;g++) s+=part[(size_t)((g<<3)+co)*32768+px];
            v=gelu_f(s+b1s[co]);
        }
        t1T[co][pos]=v;
    }
    __syncthreads();
    int px=tid&127, half=tid>>7;
    int ly=px>>6, x=px&63, gy=y0+ly;
    float acc[4];
    #pragma unroll
    for(int qq=0;qq<4;qq++) acc[qq]=b2[half*4+qq];
    for(int ci=0;ci<8;ci++){
        #pragma unroll
        for(int dy=-1;dy<=1;dy++){
            int tr=ly+1+dy;
            #pragma unroll
            for(int dx=-1;dx<=1;dx++){
                int xx=x+dx;
                float v=(xx>=0&&xx<64)?t1T[ci][tr*64+xx]:0.f;
                int ti=(dy+1)*3+(dx+1);
                #pragma unroll
                for(int qq=0;qq<4;qq++) acc[qq]+=v*w2s[((half*4+qq)*8+ci)*9+ti];
            }
        }
    }
    float s4=0.f, sa4=0.f;
    #pragma unroll
    for(int qq=0;qq<4;qq++){
        float cv=gelu_f(acc[qq]);
        carrier[((size_t)((b<<3)+half*4+qq)<<12)+(gy<<6)+x]=cv;
        s4+=cv; sa4+=fabsf(cv);
    }
    sumS[half][px]=s4; saS[half][px]=sa4;
    __syncthreads();
    float aS=0.f, aMn=1e30f, aMx=-1e30f;
    if(half==0){
        float cmv=(sumS[0][px]+sumS[1][px])*0.125f;
        float av =(saS[0][px]+saS[1][px])*0.125f;
        int gp=(b<<12)+(gy<<6)+x;
        cm[gp]=cmv;
        absc[gp]=av;
        aS=av; aMn=av; aMx=av;
    }
    rS[tid]=aS; rMn[tid]=aMn; rMx[tid]=aMx;
    __syncthreads();
    for(int st=128;st>0;st>>=1){
        if(tid<st){
            rS[tid]+=rS[tid+st];
            rMn[tid]=fminf(rMn[tid],rMn[tid+st]);
            rMx[tid]=fmaxf(rMx[tid],rMx[tid+st]);
        }
        __syncthreads();
    }
    if(tid==0){
        bpart[bl*8+0]=rS[0];
        bpart[bl*8+3]=rMn[0];
        bpart[bl*8+4]=rMx[0];
    }
}

// ---------------- k_resp: chp + 9x9 bank conv + csraw + top2 softmax ----------------
// grid 256: bl = b*32+band, band = 2 output rows; 2 threads/px x 4 protos
__global__ void __launch_bounds__(256) k_resp(const float* __restrict__ cm,
    const float* __restrict__ klg, const float* __restrict__ theta,
    const float* __restrict__ length, const float* __restrict__ width,
    const float* __restrict__ plog,
    float* __restrict__ csraw, float* __restrict__ ss0, float* __restrict__ bpart){
    __shared__ float cmT[768];       // rows y0-5..y0+6
    __shared__ float chpT[640];      // rows y0-4..y0+5
    __shared__ float klS[648];
    __shared__ float mg[128][8];
    __shared__ float rMn[256], rMx[256];
    int tid=threadIdx.x, bl=blockIdx.x;
    int b=bl>>5, band=bl&31, y0=band<<1;
    for(int i=tid;i<648;i+=256) klS[i]=klg[i];
    for(int j=tid;j<768;j+=256){
        int r=j>>6, x=j&63;
        int gy=y0-5+r;
        cmT[j]=(gy>=0&&gy<64)?cm[(b<<12)+(gy<<6)+x]:0.f;
    }
    __syncthreads();
    for(int j=tid;j<640;j+=256){
        int rh=j>>6, x=j&63;
        int gy=y0-4+rh;
        float v=0.f;
        if(gy>=0&&gy<64){
            float s=0.f;
            #pragma unroll
            for(int dy=-1;dy<=1;dy++){
                #pragma unroll
                for(int dx=-1;dx<=1;dx++){
                    int xx=x+dx;
                    if(xx>=0&&xx<64) s+=cmT[(rh+1+dy)*64+xx];
                }
            }
            v=cmT[(rh+1)*64+x]-s*(1.f/9.f);
        }
        chpT[j]=v;
    }
    __syncthreads();
    int px=tid&127, half=tid>>7;
    int ly=px>>6, x=px&63, gy=y0+ly;
    int gp=(b<<12)+(gy<<6)+x;
    float acc[4];
    #pragma unroll
    for(int qq=0;qq<4;qq++) acc[qq]=0.f;
    float cs=0.f;
    for(int dy=-4;dy<=4;dy++){
        int lr=ly+dy+4;
        for(int dx=-4;dx<=4;dx++){
            int xx=x+dx;
            float v=(xx>=0&&xx<64)?chpT[lr*64+xx]:0.f;
            int ti=(dy+4)*9+(dx+4);
            #pragma unroll
            for(int qq=0;qq<4;qq++) acc[qq]+=v*klS[(half*4+qq)*81+ti];
            if(half==0 && dy>=-1&&dy<=1&&dx>=-1&&dx<=1) cs+=fabsf(v);
        }
    }
    float ta=tanhf(theta[gp])*PI_F;
    float lv=sigm_f(length[gp])*0.85f+0.25f;
    float wv=sigm_f(width[gp])*0.22f+0.08f;
    const float Ls[3]={0.45f,0.75f,1.05f};
    const float Ws[3]={0.14f,0.20f,0.28f};
    int pp=(gy<<6)+x;
    float m1=-1e30f,m2=-1e30f,r1v=0.f,r2v=0.f;
    #pragma unroll
    for(int qq=0;qq<4;qq++){
        int q=half*4+qq;
        float ang=2.f*PI_F*(float)q*0.125f;
        float la=Ls[q%3], wa=Ws[(q/3)%3];
        float bias=plog[((size_t)((b<<3)+q)<<12)+pp]
                 +1.25f*cosf(ta-ang)
                 -(lv-la)*(lv-la)*(1.f/0.08f)
                 -(wv-wa)*(wv-wa)*(1.f/0.01f);
        if(bias>m1){m2=m1;r2v=r1v;m1=bias;r1v=acc[qq];}
        else if(bias>m2){m2=bias;r2v=acc[qq];}
    }
    mg[px][half*4+0]=m1; mg[px][half*4+1]=r1v;
    mg[px][half*4+2]=m2; mg[px][half*4+3]=r2v;
    __syncthreads();
    float cMn=1e30f, cMx=-1e30f;
    if(half==0){
        float m1a=mg[px][0], r1a=mg[px][1], m2a=mg[px][2], r2a=mg[px][3];
        float m1b=mg[px][4], r1b=mg[px][5], m2b=mg[px][6], r2b=mg[px][7];
        float M1,R1,M2,R2;
        if(m1b>m1a){ M1=m1b;R1=r1b; if(m2b>m1a){M2=m2b;R2=r2b;} else {M2=m1a;R2=r1a;} }
        else       { M1=m1a;R1=r1a; if(m1b>m2a){M2=m1b;R2=r1b;} else {M2=m2a;R2=r2a;} }
        float e2=expf(M2-M1);
        float inv=1.0f/(1.0f+e2);
        ss0[gp]=R1*inv + R2*e2*inv;
        float csv=cs*(1.f/9.f);
        csraw[gp]=csv;
        cMn=csv; cMx=csv;
    }
    rMn[tid]=cMn; rMx[tid]=cMx;
    __syncthreads();
    for(int st=128;st>0;st>>=1){
        if(tid<st){
            rMn[tid]=fminf(rMn[tid],rMn[tid+st]);
            rMx[tid]=fmaxf(rMx[tid],rMx[tid+st]);
        }
        __syncthreads();
    }
    if(tid==0){
        bpart[bl*8+1]=rMn[0];
        bpart[bl*8+2]=rMx[0];
    }
}

// ---------------- k_gate: tiled gate pipeline, 64 blocks (8 segments/batch) ----------------
__global__ void __launch_bounds__(256) k_gate(const float* __restrict__ csraw,
    const float* __restrict__ absc, const float* __restrict__ objn,
    const float* __restrict__ alpha, const float* __restrict__ bpart,
    float* __restrict__ sg){
    __shared__ float evT[1280];   // rows y0-6 .. y0+13
    __shared__ float gmT[1280];   // sigm gate, same rows
    __shared__ float eT[1024];    // erode, rows y0-4 .. y0+11
    __shared__ float m1T[768];    // dilate, rows y0-2 .. y0+9
    __shared__ float obT[640];    // sigm(objn), rows y0-1 .. y0+8
    __shared__ float red5[5];
    int blk=blockIdx.x, tid=threadIdx.x;
    int b=blk>>3, y0=(blk&7)<<3;
    if(tid==0){
        float sm=0.f, cmn=1e30f, cmx=-1e30f, amn=1e30f, amx=-1e30f;
        for(int j=0;j<32;j++){
            const float* bp=&bpart[(b*32+j)*8];
            sm+=bp[0];
            cmn=fminf(cmn,bp[1]); cmx=fmaxf(cmx,bp[2]);
            amn=fminf(amn,bp[3]); amx=fmaxf(amx,bp[4]);
        }
        float den=fmaxf(sm*(1.0f/4096.0f),1e-6f);
        red5[0]=den; red5[1]=cmn; red5[2]=cmx; red5[3]=amn/den; red5[4]=amx/den;
    }
    __syncthreads();
    float den=red5[0], cmn=red5[1], dmn=red5[3];
    float cinv = 1.0f/fmaxf(red5[2]-cmn,1e-6f);
    float dinv = 1.0f/fmaxf(red5[4]-dmn,1e-6f);
    for(int j=tid;j<1280;j+=256){
        int r=j>>6, x=j&63; int gy=y0-6+r;
        float ev=0.f;
        if(gy>=0&&gy<64){
            int gp=(b<<12)+(gy<<6)+x;
            float cs=(csraw[gp]-cmn)*cinv;
            float d=absc[gp]/den;
            ev=0.65f*cs+0.35f*((d-dmn)*dinv);
        }
        evT[j]=ev;
        gmT[j]=sigm_f((ev-0.2f)*(1.0f/0.08f));
    }
    for(int j=tid;j<640;j+=256){
        int r=j>>6,x=j&63; int gy=y0-1+r;
        obT[j]=(gy>=0&&gy<64)?sigm_f(objn[(b<<12)+(gy<<6)+x]):0.f;
    }
    __syncthreads();
    // erode: mask=ev>=THR; e=1 iff all valid 5x5 neighbors have mask==1
    for(int j=tid;j<1024;j+=256){
        int r=j>>6,x=j&63; int gy=y0-4+r;
        float m=0.f;
        if(gy>=0&&gy<64){
            m=1.f;
            for(int dy=-2;dy<=2;dy++){int yy=gy+dy; if(yy<0||yy>=64)continue;
                int lr=yy-(y0-6);
                for(int dx=-2;dx<=2;dx++){int xx=x+dx; if(xx<0||xx>=64)continue;
                    if(evT[(lr<<6)+xx]<0.2f) m=0.f;}}
        }
        eT[j]=m;
    }
    __syncthreads();
    // dilate e -> m1
    for(int j=tid;j<768;j+=256){
        int r=j>>6,x=j&63; int gy=y0-2+r;
        float m=0.f;
        if(gy>=0&&gy<64){
            m=-1e30f;
            for(int dy=-2;dy<=2;dy++){int yy=gy+dy; if(yy<0||yy>=64)continue;
                int lr=yy-(y0-4);
                for(int dx=-2;dx<=2;dx++){int xx=x+dx; if(xx<0||xx>=64)continue;
                    m=fmaxf(m,eT[(lr<<6)+xx]);}}
        }
        m1T[j]=m;
    }
    __syncthreads();
    // final 512 px
    for(int k=0;k<2;k++){
        int p=tid+(k<<8);
        int ly=p>>6, x=p&63; int gy=y0+ly;
        int gp=(b<<12)+(gy<<6)+x;
        float m2=-1e30f, gx=-1e30f;
        for(int dy=-2;dy<=2;dy++){int yy=gy+dy; if(yy<0||yy>=64)continue;
            int lr1=yy-(y0-2), lr2=yy-(y0-6);
            for(int dx=-2;dx<=2;dx++){int xx=x+dx; if(xx<0||xx>=64)continue;
                m2=fmaxf(m2,m1T[(lr1<<6)+xx]);
                gx=fmaxf(gx,gmT[(lr2<<6)+xx]);}}
        float s=0.f;
        for(int dy=-1;dy<=1;dy++){int yy=gy+dy; if(yy<0||yy>=64)continue;
            int lr=yy-(y0-1);
            for(int dx=-1;dx<=1;dx++){int xx=x+dx; if(xx<0||xx>=64)continue;
                s+=obT[(lr<<6)+xx];}}
        float blob=s*(1.0f/9.0f);
        float gate=gx*m2;
        float d=absc[gp]/den;
        sg[gp]=sigm_f(alpha[gp])*blob*gate*(0.7f+0.3f*fminf(fmaxf(d,0.f),2.f));
    }
}

// ---------------- k_out: h + pm2 fused, 512 blocks of 16 f4 px ----------------
__global__ void __launch_bounds__(256) k_out(const float* __restrict__ ss0,
    const float* __restrict__ sg, const float* __restrict__ theta,
    const float* __restrict__ curv, const float* __restrict__ carrier,
    const float* __restrict__ w3, const float* __restrict__ b3,
    const float* __restrict__ w4, const float* __restrict__ b4,
    float* __restrict__ out){
    __shared__ float hS[8][64];      // 2 KB
    __shared__ float w4s[768*8];     // 24 KB
    __shared__ float b4s[768];
    __shared__ float wl[96];
    __shared__ float bl3[8];
    int tid=threadIdx.x;
    int bln=blockIdx.x;              // 0..511
    for(int i=tid;i<6144;i+=256) w4s[i]=w4[i];
    for(int i=tid;i<768;i+=256) b4s[i]=b4[i];
    if(tid<96) wl[tid]=w3[tid];
    if(tid<8) bl3[tid]=b3[tid];
    __syncthreads();

    if(tid<64){
        int gp=bln*64+tid;
        int b=gp>>12, p=gp&4095, y=p>>6, x=p&63;
        const float* base = ss0 + (b<<12);
        float s=0.f;
        for(int dy=-1;dy<=1;dy++){int yy=y+dy; if(yy<0||yy>=64)continue;
            for(int dx=-1;dx<=1;dx++){int xx=x+dx;if(xx<0||xx>=64)continue;
                s+=base[(yy<<6)+xx];}}
        float ss1 = base[p]-s*(1.0f/9.0f);
        float cu = tanhf(curv[gp]);
        float ssv = sg[gp]*ss1*(1.0f+0.15f*cu);
        float ta = tanhf(theta[gp])*PI_F;
        float dxv=cosf(ta), dyv=sinf(ta);
        float car[8];
        #pragma unroll
        for(int ci=0;ci<8;ci++) car[ci]=carrier[((size_t)((b<<3)+ci)<<12)+p];
        #pragma unroll
        for(int co=0;co<8;co++){
            const float* w=&wl[co*12];
            float t = w[8] + w[9]*dxv + w[10]*dyv + w[11]*cu;
            #pragma unroll
            for(int ci=0;ci<8;ci++) t += w[ci]*car[ci];
            hS[co][tid] = gelu_f(bl3[co] + ssv*t);
        }
    }
    __syncthreads();

    int px4 = tid&15;          // f4 px within block
    int cg = tid>>4;           // 0..15, 48 co each
    int q0 = bln*16 + px4;     // GLOBAL f4 index (0..8191)
    int b = q0>>10;
    int ql = q0 & 1023;        // within-batch f4 index
    float4 hv[8];
    #pragma unroll
    for(int ci=0;ci<8;ci++) hv[ci]=*(const float4*)&hS[ci][px4<<2];
    float4* o4=(float4*)out;
    for(int k=0;k<48;k++){
        int co=cg*48+k;
        float bb=b4s[co];
        float4 o=make_float4(bb,bb,bb,bb);
        const float* w=&w4s[co<<3];
        #pragma unroll
        for(int ci=0;ci<8;ci++){
            float wv=w[ci];
            o.x+=wv*hv[ci].x; o.y+=wv*hv[ci].y; o.z+=wv*hv[ci].z; o.w+=wv*hv[ci].w;
        }
        nt_store4(&o4[(size_t)(b*768+co)*1024 + ql], o);
    }
}

extern "C" void kernel_launch(void* const* d_in, const int* in_sizes, int n_in,
                              void* d_out, int out_size, void* d_ws, size_t ws_size,
                              hipStream_t stream) {
    const float* fm     =(const float*)d_in[0];
    const float* theta  =(const float*)d_in[1];
    const float* length =(const float*)d_in[2];
    const float* width  =(const float*)d_in[3];
    const float* curv   =(const float*)d_in[4];
    const float* alpha  =(const float*)d_in[5];
    const float* objn   =(const float*)d_in[6];
    const float* plog   =(const float*)d_in[7];
    const float* fp1w   =(const float*)d_in[8];
    const float* fp1b   =(const float*)d_in[9];
    const float* fp2w   =(const float*)d_in[10];
    const float* fp2b   =(const float*)d_in[11];
    const float* pm1w   =(const float*)d_in[12];
    const float* pm1b   =(const float*)d_in[13];
    const float* pm2w   =(const float*)d_in[14];
    const float* pm2b   =(const float*)d_in[15];
    const float* pdelta =(const float*)d_in[16];

    float* ws=(float*)d_ws;
    float* part    = ws;                  // 2097152 (all planes live)
    float* carrier = part + 2097152;      // 262144
    float* absc    = carrier + 262144;    // 32768
    float* csraw   = absc + 32768;        // 32768
    float* ss0     = csraw + 32768;       // 32768
    float* sg      = ss0 + 32768;         // 32768
    float* cm      = sg + 32768;          // 32768
    float* bpart   = cm + 32768;          // 2048
    float* klg     = bpart + 2048;        // 648
    float* out     = (float*)d_out;

    k_conv1<<<dim3(64,8), 256, 0, stream>>>(fm, fp1w, pdelta, part, klg);
    k_conv2<<<256, 256, 0, stream>>>(part, fp1b, fp2w, fp2b, carrier, cm, absc, bpart);
    k_resp <<<256, 256, 0, stream>>>(cm, klg, theta, length, width, plog,
                                     csraw, ss0, bpart);
    k_gate <<<64, 256, 0, stream>>>(csraw, absc, objn, alpha, bpart, sg);
    k_out  <<<512, 256, 0, stream>>>(ss0, sg, theta, curv, carrier,
                                     pm1w, pm1b, pm2w, pm2b, out);
}

// Round 7
// 281.688 us; speedup vs baseline: 1.2455x; 1.0100x over previous
//
#include <hip/hip_runtime.h>
#include <math.h>

#define PI_F 3.14159265358979323846f

__device__ __forceinline__ float gelu_f(float x){ return 0.5f*x*(1.0f+erff(x*0.7071067811865475f)); }
__device__ __forceinline__ float sigm_f(float x){ return 1.0f/(1.0f+expf(-x)); }

// native vector type for nontemporal builtins (HIP_vector_type is rejected by the builtin)
typedef float nf4 __attribute__((ext_vector_type(4)));
__device__ __forceinline__ float4 nt_load4(const float4* p){
    nf4 v = __builtin_nontemporal_load((const nf4*)p);
    return make_float4(v.x, v.y, v.z, v.w);
}
__device__ __forceinline__ void nt_store4(float4* p, float4 v){
    nf4 w; w.x=v.x; w.y=v.y; w.z=v.z; w.w=v.w;
    __builtin_nontemporal_store(w, (nf4*)p);
}

// B=8, H=W=64, HW=4096, NP=32768, FC=768, RC=8, P=8, K=9, G=8 channel groups

// ---------------- K1: fp1 1x1 conv 768->8, channel-split partials + bank fold ----------------
// grid (64,8): chunk = b*8+sub (128 f4 each), g = channel group (96 ch)
__global__ void __launch_bounds__(256) k_conv1(const float* __restrict__ fm,
                        const float* __restrict__ w1, const float* __restrict__ pd,
                        float* __restrict__ part, float* __restrict__ klg){
    int chunk = blockIdx.x;   // 0..63
    int g = blockIdx.y;       // 0..7
    int tid = threadIdx.x;
    __shared__ float wl[96*8];
    __shared__ float4 comb[8][128];   // 16 KB
    for (int i=tid;i<768;i+=256){ int c=i>>3, co=i&7; wl[i]=w1[co*768 + g*96 + c]; }
    __syncthreads();
    int b = chunk>>3;
    int f4 = tid&127, half = tid>>7;
    int q0 = ((chunk&7)<<7) + f4;   // f4 offset within batch plane (0..1023)
    const float4* fm4 = (const float4*)fm;
    float4 acc[8];
    #pragma unroll
    for(int co=0;co<8;co++) acc[co]=make_float4(0.f,0.f,0.f,0.f);
    int basec = b*768 + g*96 + half*48;
    #pragma unroll 4
    for(int c=0;c<48;c++){
        float4 x = nt_load4(&fm4[(size_t)(basec+c)*1024 + q0]);
        int ch = half*48 + c;
        #pragma unroll
        for(int co=0;co<8;co++){
            float wv = wl[(ch<<3)+co];
            acc[co].x += wv*x.x; acc[co].y += wv*x.y; acc[co].z += wv*x.z; acc[co].w += wv*x.w;
        }
    }
    if(half==1){
        #pragma unroll
        for(int co=0;co<8;co++) comb[co][f4]=acc[co];
    }
    __syncthreads();
    if(half==0){
        float4* p4 = (float4*)part;
        int gq = (b<<10) + q0;
        #pragma unroll
        for(int co=0;co<8;co++){
            float4 o = comb[co][f4];
            o.x+=acc[co].x; o.y+=acc[co].y; o.z+=acc[co].z; o.w+=acc[co].w;
            p4[(size_t)((g<<3)+co)*8192 + gq] = o;
        }
    }

    // ---- bank build (one block only) ----
    if(chunk==0 && g==0){
        __shared__ float ridge[648];
        __shared__ float pmS[8], pdenS[8];
        for(int t=tid;t<648;t+=256){
            int p=t/81, idx=t-p*81;
            int i=idx/9, j=idx-i*9;
            float ay=-1.f+0.25f*(float)i;
            float ax=-1.f+0.25f*(float)j;
            float ang=2.f*PI_F*(float)p*0.125f;
            const float Ls[3]={0.45f,0.75f,1.05f};
            const float Ws[3]={0.14f,0.20f,0.28f};
            float L=Ls[p%3], Wd=Ws[(p/3)%3];
            float cs=cosf(ang), sn=sinf(ang);
            float xr=ax*cs+ay*sn;
            float yr=-ax*sn+ay*cs;
            float tp=1.f-fminf(fabsf(xr)/L,1.f);
            float taper=powf(tp,1.5f);
            float core=expf(-0.5f*((xr/L)*(xr/L)+(yr/Wd)*(yr/Wd)));
            ridge[t]=taper*core*fmaxf(1.f-(yr/Wd)*(yr/Wd),0.f);
        }
        __syncthreads();
        {
            int p=tid>>5, k=tid&31;
            float s=0.f;
            for(int e=k;e<81;e+=32) s+=ridge[p*81+e];
            for(int off=16;off>0;off>>=1) s+=__shfl_down(s,off,32);
            if(k==0) pmS[p]=s*(1.f/81.f);
        }
        __syncthreads();
        {
            int p=tid>>5, k=tid&31;
            float m=pmS[p];
            float s=0.f;
            for(int e=k;e<81;e+=32) s+=fabsf(ridge[p*81+e]-m);
            for(int off=16;off>0;off>>=1) s+=__shfl_down(s,off,32);
            if(k==0) pdenS[p]=fmaxf(s,1e-6f);
        }
        __syncthreads();
        for(int t=tid;t<648;t+=256){
            int p=t/81;
            klg[t]=(ridge[t]-pmS[p])/pdenS[p]+0.05f*pd[t];
        }
    }
}

// ---------------- k_conv2: partial-sum + gelu + 3x3 conv 8->8 -> carrier, cm, absc ----------------
// grid 512: bl = b*64 + y, ONE output row per block (2 blocks/CU)
__global__ void __launch_bounds__(256) k_conv2(const float* __restrict__ part,
    const float* __restrict__ b1, const float* __restrict__ w2, const float* __restrict__ b2,
    float* __restrict__ carrier, float* __restrict__ cm, float* __restrict__ absc,
    float* __restrict__ bpart){
    __shared__ float t1T[8][3][64];  // rows y-1..y+1, 6 KB
    __shared__ float w2s[576];
    __shared__ float b1s[8];
    __shared__ float sumS[4][64];
    __shared__ float saS[4][64];
    int tid=threadIdx.x, bl=blockIdx.x;
    int b=bl>>6, y=bl&63;
    for(int i=tid;i<576;i+=256) w2s[i]=w2[i];
    if(tid<8) b1s[tid]=b1[tid];
    __syncthreads();
    // stage t1 rows y-1..y+1 (8 ci x 3 rows x 64)
    for(int j=tid;j<1536;j+=256){
        int ci=j/192, rem=j-ci*192, r=rem>>6, x=rem&63;
        int gy=y-1+r;
        float v=0.f;
        if(gy>=0 && gy<64){
            int px=(b<<12)+(gy<<6)+x;
            float s=0.f;
            #pragma unroll
            for(int g=0;g<8;g++) s+=part[(size_t)((g<<3)+ci)*32768+px];
            v=gelu_f(s+b1s[ci]);
        }
        t1T[ci][r][x]=v;
    }
    __syncthreads();
    int x=tid&63, cg=tid>>6;   // cg 0..3, each owns 2 output channels
    float acc[2];
    #pragma unroll
    for(int qq=0;qq<2;qq++) acc[qq]=b2[cg*2+qq];
    for(int ci=0;ci<8;ci++){
        #pragma unroll
        for(int r=0;r<3;r++){
            #pragma unroll
            for(int dx=-1;dx<=1;dx++){
                int xx=x+dx;
                float v=(xx>=0&&xx<64)?t1T[ci][r][xx]:0.f;
                int ti=r*3+(dx+1);
                #pragma unroll
                for(int qq=0;qq<2;qq++) acc[qq]+=v*w2s[(((cg*2+qq)*8+ci)*9)+ti];
            }
        }
    }
    float s2=0.f, sa2=0.f;
    #pragma unroll
    for(int qq=0;qq<2;qq++){
        float cv=gelu_f(acc[qq]);
        carrier[((size_t)((b<<3)+cg*2+qq)<<12)+(y<<6)+x]=cv;
        s2+=cv; sa2+=fabsf(cv);
    }
    sumS[cg][x]=s2; saS[cg][x]=sa2;
    __syncthreads();
    if(cg==0){   // tid 0..63 = wave 0
        float cmv=(sumS[0][x]+sumS[1][x]+sumS[2][x]+sumS[3][x])*0.125f;
        float av =(saS[0][x]+saS[1][x]+saS[2][x]+saS[3][x])*0.125f;
        int gp=(b<<12)+(y<<6)+x;
        cm[gp]=cmv;
        absc[gp]=av;
        float s=av, mn=av, mx=av;
        #pragma unroll
        for(int off=32;off>0;off>>=1){
            s += __shfl_down(s,off);
            mn = fminf(mn,__shfl_down(mn,off));
            mx = fmaxf(mx,__shfl_down(mx,off));
        }
        if(x==0){
            bpart[bl*8+0]=s;
            bpart[bl*8+3]=mn;
            bpart[bl*8+4]=mx;
        }
    }
}

// ---------------- k_resp: chp + 9x9 bank conv + csraw + top2 softmax ----------------
// grid 512: bl = b*64+y, ONE output row per block; 4 thread-groups x 2 protos
__global__ void __launch_bounds__(256) k_resp(const float* __restrict__ cm,
    const float* __restrict__ klg, const float* __restrict__ theta,
    const float* __restrict__ length, const float* __restrict__ width,
    const float* __restrict__ plog,
    float* __restrict__ csraw, float* __restrict__ ss0, float* __restrict__ bpart){
    __shared__ float cmT[704];       // rows y-5..y+5 (11 rows)
    __shared__ float chpT[576];      // rows y-4..y+4 (9 rows)
    __shared__ float klS[648];
    __shared__ float mg[64][16];
    int tid=threadIdx.x, bl=blockIdx.x;
    int b=bl>>6, y=bl&63;
    for(int i=tid;i<648;i+=256) klS[i]=klg[i];
    for(int j=tid;j<704;j+=256){
        int r=j>>6, x=j&63;
        int gy=y-5+r;
        cmT[j]=(gy>=0&&gy<64)?cm[(b<<12)+(gy<<6)+x]:0.f;
    }
    __syncthreads();
    for(int j=tid;j<576;j+=256){
        int rh=j>>6, x=j&63;      // rh 0..8 <-> gy = y-4+rh, cmT row rh+1
        int gy=y-4+rh;
        float v=0.f;
        if(gy>=0&&gy<64){
            float s=0.f;
            #pragma unroll
            for(int dy=0;dy<3;dy++){
                #pragma unroll
                for(int dx=-1;dx<=1;dx++){
                    int xx=x+dx;
                    if(xx>=0&&xx<64) s+=cmT[(rh+dy)*64+xx];
                }
            }
            v=cmT[(rh+1)*64+x]-s*(1.f/9.f);
        }
        chpT[j]=v;
    }
    __syncthreads();
    int x=tid&63, qg=tid>>6;   // qg 0..3, protos qg*2, qg*2+1
    int gp=(b<<12)+(y<<6)+x;
    float acc[2]={0.f,0.f};
    float cs=0.f;
    for(int dy=-4;dy<=4;dy++){
        int lr=dy+4;
        for(int dx=-4;dx<=4;dx++){
            int xx=x+dx;
            float v=(xx>=0&&xx<64)?chpT[lr*64+xx]:0.f;
            int ti=lr*9+(dx+4);
            acc[0]+=v*klS[(qg*2)*81+ti];
            acc[1]+=v*klS[(qg*2+1)*81+ti];
            if(qg==0 && dy>=-1&&dy<=1&&dx>=-1&&dx<=1) cs+=fabsf(v);
        }
    }
    float ta=tanhf(theta[gp])*PI_F;
    float lv=sigm_f(length[gp])*0.85f+0.25f;
    float wv=sigm_f(width[gp])*0.22f+0.08f;
    const float Ls[3]={0.45f,0.75f,1.05f};
    const float Ws[3]={0.14f,0.20f,0.28f};
    int pp=(y<<6)+x;
    float bias[2];
    #pragma unroll
    for(int qq=0;qq<2;qq++){
        int q=qg*2+qq;
        float ang=2.f*PI_F*(float)q*0.125f;
        float la=Ls[q%3], wa=Ws[(q/3)%3];
        bias[qq]=plog[((size_t)((b<<3)+q)<<12)+pp]
               +1.25f*cosf(ta-ang)
               -(lv-la)*(lv-la)*(1.f/0.08f)
               -(wv-wa)*(wv-wa)*(1.f/0.01f);
    }
    float m1,r1,m2,r2;
    if(bias[1]>bias[0]){ m1=bias[1];r1=acc[1]; m2=bias[0];r2=acc[0]; }
    else               { m1=bias[0];r1=acc[0]; m2=bias[1];r2=acc[1]; }
    mg[x][qg*4+0]=m1; mg[x][qg*4+1]=r1; mg[x][qg*4+2]=m2; mg[x][qg*4+3]=r2;
    __syncthreads();
    if(qg==0){   // wave 0
        float M1=mg[x][0],R1=mg[x][1],M2=mg[x][2],R2=mg[x][3];
        #pragma unroll
        for(int g=1;g<4;g++){
            float m1b=mg[x][g*4],r1b=mg[x][g*4+1],m2b=mg[x][g*4+2],r2b=mg[x][g*4+3];
            if(m1b>M1){
                float nM2,nR2;
                if(m2b>M1){nM2=m2b;nR2=r2b;} else {nM2=M1;nR2=R1;}
                M1=m1b;R1=r1b;M2=nM2;R2=nR2;
            } else if(m1b>M2){
                M2=m1b;R2=r1b;
            }
        }
        float e2=expf(M2-M1);
        float inv=1.0f/(1.0f+e2);
        ss0[gp]=R1*inv + R2*e2*inv;
        float csv=cs*(1.f/9.f);
        csraw[gp]=csv;
        float mn=csv, mx=csv;
        #pragma unroll
        for(int off=32;off>0;off>>=1){
            mn=fminf(mn,__shfl_down(mn,off));
            mx=fmaxf(mx,__shfl_down(mx,off));
        }
        if(x==0){
            bpart[bl*8+1]=mn;
            bpart[bl*8+2]=mx;
        }
    }
}

// ---------------- k_gate: tiled gate pipeline, 64 blocks (8 segments/batch) ----------------
__global__ void __launch_bounds__(256) k_gate(const float* __restrict__ csraw,
    const float* __restrict__ absc, const float* __restrict__ objn,
    const float* __restrict__ alpha, const float* __restrict__ bpart,
    float* __restrict__ sg){
    __shared__ float evT[1280];   // rows y0-6 .. y0+13
    __shared__ float gmT[1280];   // sigm gate, same rows
    __shared__ float eT[1024];    // erode, rows y0-4 .. y0+11
    __shared__ float m1T[768];    // dilate, rows y0-2 .. y0+9
    __shared__ float obT[640];    // sigm(objn), rows y0-1 .. y0+8
    __shared__ float red5[5];
    int blk=blockIdx.x, tid=threadIdx.x;
    int b=blk>>3, y0=(blk&7)<<3;
    if(tid==0){
        float sm=0.f, cmn=1e30f, cmx=-1e30f, amn=1e30f, amx=-1e30f;
        for(int j=0;j<64;j++){
            const float* bp=&bpart[(b*64+j)*8];
            sm+=bp[0];
            cmn=fminf(cmn,bp[1]); cmx=fmaxf(cmx,bp[2]);
            amn=fminf(amn,bp[3]); amx=fmaxf(amx,bp[4]);
        }
        float den=fmaxf(sm*(1.0f/4096.0f),1e-6f);
        red5[0]=den; red5[1]=cmn; red5[2]=cmx; red5[3]=amn/den; red5[4]=amx/den;
    }
    __syncthreads();
    float den=red5[0], cmn=red5[1], dmn=red5[3];
    float cinv = 1.0f/fmaxf(red5[2]-cmn,1e-6f);
    float dinv = 1.0f/fmaxf(red5[4]-dmn,1e-6f);
    for(int j=tid;j<1280;j+=256){
        int r=j>>6, x=j&63; int gy=y0-6+r;
        float ev=0.f;
        if(gy>=0&&gy<64){
            int gp=(b<<12)+(gy<<6)+x;
            float cs=(csraw[gp]-cmn)*cinv;
            float d=absc[gp]/den;
            ev=0.65f*cs+0.35f*((d-dmn)*dinv);
        }
        evT[j]=ev;
        gmT[j]=sigm_f((ev-0.2f)*(1.0f/0.08f));
    }
    for(int j=tid;j<640;j+=256){
        int r=j>>6,x=j&63; int gy=y0-1+r;
        obT[j]=(gy>=0&&gy<64)?sigm_f(objn[(b<<12)+(gy<<6)+x]):0.f;
    }
    __syncthreads();
    // erode: mask=ev>=THR; e=1 iff all valid 5x5 neighbors have mask==1
    for(int j=tid;j<1024;j+=256){
        int r=j>>6,x=j&63; int gy=y0-4+r;
        float m=0.f;
        if(gy>=0&&gy<64){
            m=1.f;
            for(int dy=-2;dy<=2;dy++){int yy=gy+dy; if(yy<0||yy>=64)continue;
                int lr=yy-(y0-6);
                for(int dx=-2;dx<=2;dx++){int xx=x+dx; if(xx<0||xx>=64)continue;
                    if(evT[(lr<<6)+xx]<0.2f) m=0.f;}}
        }
        eT[j]=m;
    }
    __syncthreads();
    // dilate e -> m1
    for(int j=tid;j<768;j+=256){
        int r=j>>6,x=j&63; int gy=y0-2+r;
        float m=0.f;
        if(gy>=0&&gy<64){
            m=-1e30f;
            for(int dy=-2;dy<=2;dy++){int yy=gy+dy; if(yy<0||yy>=64)continue;
                int lr=yy-(y0-4);
                for(int dx=-2;dx<=2;dx++){int xx=x+dx; if(xx<0||xx>=64)continue;
                    m=fmaxf(m,eT[(lr<<6)+xx]);}}
        }
        m1T[j]=m;
    }
    __syncthreads();
    // final 512 px
    for(int k=0;k<2;k++){
        int p=tid+(k<<8);
        int ly=p>>6, x=p&63; int gy=y0+ly;
        int gp=(b<<12)+(gy<<6)+x;
        float m2=-1e30f, gx=-1e30f;
        for(int dy=-2;dy<=2;dy++){int yy=gy+dy; if(yy<0||yy>=64)continue;
            int lr1=yy-(y0-2), lr2=yy-(y0-6);
            for(int dx=-2;dx<=2;dx++){int xx=x+dx; if(xx<0||xx>=64)continue;
                m2=fmaxf(m2,m1T[(lr1<<6)+xx]);
                gx=fmaxf(gx,gmT[(lr2<<6)+xx]);}}
        float s=0.f;
        for(int dy=-1;dy<=1;dy++){int yy=gy+dy; if(yy<0||yy>=64)continue;
            int lr=yy-(y0-1);
            for(int dx=-1;dx<=1;dx++){int xx=x+dx; if(xx<0||xx>=64)continue;
                s+=obT[(lr<<6)+xx];}}
        float blob=s*(1.0f/9.0f);
        float gate=gx*m2;
        float d=absc[gp]/den;
        sg[gp]=sigm_f(alpha[gp])*blob*gate*(0.7f+0.3f*fminf(fmaxf(d,0.f),2.f));
    }
}

// ---------------- k_out: h + pm2 fused, 512 blocks of 16 f4 px ----------------
__global__ void __launch_bounds__(256) k_out(const float* __restrict__ ss0,
    const float* __restrict__ sg, const float* __restrict__ theta,
    const float* __restrict__ curv, const float* __restrict__ carrier,
    const float* __restrict__ w3, const float* __restrict__ b3,
    const float* __restrict__ w4, const float* __restrict__ b4,
    float* __restrict__ out){
    __shared__ float hS[8][64];      // 2 KB
    __shared__ float w4s[768*8];     // 24 KB
    __shared__ float b4s[768];
    __shared__ float wl[96];
    __shared__ float bl3[8];
    int tid=threadIdx.x;
    int bln=blockIdx.x;              // 0..511
    for(int i=tid;i<6144;i+=256) w4s[i]=w4[i];
    for(int i=tid;i<768;i+=256) b4s[i]=b4[i];
    if(tid<96) wl[tid]=w3[tid];
    if(tid<8) bl3[tid]=b3[tid];
    __syncthreads();

    if(tid<64){
        int gp=bln*64+tid;
        int b=gp>>12, p=gp&4095, y=p>>6, x=p&63;
        const float* base = ss0 + (b<<12);
        float s=0.f;
        for(int dy=-1;dy<=1;dy++){int yy=y+dy; if(yy<0||yy>=64)continue;
            for(int dx=-1;dx<=1;dx++){int xx=x+dx;if(xx<0||xx>=64)continue;
                s+=base[(yy<<6)+xx];}}
        float ss1 = base[p]-s*(1.0f/9.0f);
        float cu = tanhf(curv[gp]);
        float ssv = sg[gp]*ss1*(1.0f+0.15f*cu);
        float ta = tanhf(theta[gp])*PI_F;
        float dxv=cosf(ta), dyv=sinf(ta);
        float car[8];
        #pragma unroll
        for(int ci=0;ci<8;ci++) car[ci]=carrier[((size_t)((b<<3)+ci)<<12)+p];
        #pragma unroll
        for(int co=0;co<8;co++){
            const float* w=&wl[co*12];
            float t = w[8] + w[9]*dxv + w[10]*dyv + w[11]*cu;
            #pragma unroll
            for(int ci=0;ci<8;ci++) t += w[ci]*car[ci];
            hS[co][tid] = gelu_f(bl3[co] + ssv*t);
        }
    }
    __syncthreads();

    int px4 = tid&15;          // f4 px within block
    int cg = tid>>4;           // 0..15, 48 co each
    int q0 = bln*16 + px4;     // GLOBAL f4 index (0..8191)
    int b = q0>>10;
    int ql = q0 & 1023;        // within-batch f4 index
    float4 hv[8];
    #pragma unroll
    for(int ci=0;ci<8;ci++) hv[ci]=*(const float4*)&hS[ci][px4<<2];
    float4* o4=(float4*)out;
    for(int k=0;k<48;k++){
        int co=cg*48+k;
        float bb=b4s[co];
        float4 o=make_float4(bb,bb,bb,bb);
        const float* w=&w4s[co<<3];
        #pragma unroll
        for(int ci=0;ci<8;ci++){
            float wv=w[ci];
            o.x+=wv*hv[ci].x; o.y+=wv*hv[ci].y; o.z+=wv*hv[ci].z; o.w+=wv*hv[ci].w;
        }
        nt_store4(&o4[(size_t)(b*768+co)*1024 + ql], o);
    }
}

extern "C" void kernel_launch(void* const* d_in, const int* in_sizes, int n_in,
                              void* d_out, int out_size, void* d_ws, size_t ws_size,
                              hipStream_t stream) {
    const float* fm     =(const float*)d_in[0];
    const float* theta  =(const float*)d_in[1];
    const float* length =(const float*)d_in[2];
    const float* width  =(const float*)d_in[3];
    const float* curv   =(const float*)d_in[4];
    const float* alpha  =(const float*)d_in[5];
    const float* objn   =(const float*)d_in[6];
    const float* plog   =(const float*)d_in[7];
    const float* fp1w   =(const float*)d_in[8];
    const float* fp1b   =(const float*)d_in[9];
    const float* fp2w   =(const float*)d_in[10];
    const float* fp2b   =(const float*)d_in[11];
    const float* pm1w   =(const float*)d_in[12];
    const float* pm1b   =(const float*)d_in[13];
    const float* pm2w   =(const float*)d_in[14];
    const float* pm2b   =(const float*)d_in[15];
    const float* pdelta =(const float*)d_in[16];

    float* ws=(float*)d_ws;
    float* part    = ws;                  // 2097152 (all planes live)
    float* carrier = part + 2097152;      // 262144
    float* absc    = carrier + 262144;    // 32768
    float* csraw   = absc + 32768;        // 32768
    float* ss0     = csraw + 32768;       // 32768
    float* sg      = ss0 + 32768;         // 32768
    float* cm      = sg + 32768;          // 32768
    float* bpart   = cm + 32768;          // 4096 (512 records x 8)
    float* klg     = bpart + 4096;        // 648
    float* out     = (float*)d_out;

    k_conv1<<<dim3(64,8), 256, 0, stream>>>(fm, fp1w, pdelta, part, klg);
    k_conv2<<<512, 256, 0, stream>>>(part, fp1b, fp2w, fp2b, carrier, cm, absc, bpart);
    k_resp <<<512, 256, 0, stream>>>(cm, klg, theta, length, width, plog,
                                     csraw, ss0, bpart);
    k_gate <<<64, 256, 0, stream>>>(csraw, absc, objn, alpha, bpart, sg);
    k_out  <<<512, 256, 0, stream>>>(ss0, sg, theta, curv, carrier,
                                     pm1w, pm1b, pm2w, pm2b, out);
}

// Round 9
// 246.001 us; speedup vs baseline: 1.4261x; 1.1451x over previous
//
#include <hip/hip_runtime.h>
#include <math.h>

#define PI_F 3.14159265358979323846f

__device__ __forceinline__ float gelu_f(float x){ return 0.5f*x*(1.0f+erff(x*0.7071067811865475f)); }
__device__ __forceinline__ float sigm_f(float x){ return 1.0f/(1.0f+expf(-x)); }

// native vector type for nontemporal builtins (HIP_vector_type is rejected by the builtin)
typedef float nf4 __attribute__((ext_vector_type(4)));
__device__ __forceinline__ float4 nt_load4(const float4* p){
    nf4 v = __builtin_nontemporal_load((const nf4*)p);
    return make_float4(v.x, v.y, v.z, v.w);
}
__device__ __forceinline__ void nt_store4(float4* p, float4 v){
    nf4 w; w.x=v.x; w.y=v.y; w.z=v.z; w.w=v.w;
    __builtin_nontemporal_store(w, (nf4*)p);
}

// B=8, H=W=64, HW=4096, NP=32768, FC=768, RC=8, P=8, K=9

// ---------------- k_conv1: fp1 1x1 conv 768->8 with IN-BLOCK channel reduction -> t1 ----------------
// grid 512: bln = b*64 + f4chunk; block owns 16 f4 (64 px). 16 groups x 16 threads; group g = ch 48g..48g+47
__global__ void __launch_bounds__(256) k_conv1(const float* __restrict__ fm,
                        const float* __restrict__ w1, const float* __restrict__ b1,
                        const float* __restrict__ pd,
                        float* __restrict__ t1, float* __restrict__ klg){
    __shared__ float wl[768*8];          // 24 KB, wl[c*8+co]
    __shared__ float4 pT[16][8][16];     // 32 KB partials [group][co][f4]
    int bln = blockIdx.x;
    int tid = threadIdx.x;
    int b = bln>>6;
    int q4base = (bln&63)<<4;            // f4 offset within batch plane
    for (int i=tid;i<6144;i+=256){ int c=i>>3, co=i&7; wl[i]=w1[co*768 + c]; }
    __syncthreads();
    int f4i = tid&15, grp = tid>>4;      // grp 0..15
    int q4 = q4base + f4i;
    const float4* fm4 = (const float4*)fm;
    float4 acc[8];
    #pragma unroll
    for(int co=0;co<8;co++) acc[co]=make_float4(0.f,0.f,0.f,0.f);
    int ch0 = grp*48;
    #pragma unroll 4
    for(int c=0;c<48;c++){
        int ch = ch0 + c;
        float4 x = nt_load4(&fm4[(size_t)(b*768 + ch)*1024 + q4]);
        #pragma unroll
        for(int co=0;co<8;co++){
            float wv = wl[(ch<<3)+co];
            acc[co].x += wv*x.x; acc[co].y += wv*x.y; acc[co].z += wv*x.z; acc[co].w += wv*x.w;
        }
    }
    #pragma unroll
    for(int co=0;co<8;co++) pT[grp][co][f4i]=acc[co];
    __syncthreads();
    if(tid<128){
        int co=tid>>4, fi=tid&15;
        float4 s=make_float4(0.f,0.f,0.f,0.f);
        #pragma unroll
        for(int g=0;g<16;g++){
            float4 v=pT[g][co][fi];
            s.x+=v.x; s.y+=v.y; s.z+=v.z; s.w+=v.w;
        }
        float bb=b1[co];
        float4 o;
        o.x=gelu_f(s.x+bb); o.y=gelu_f(s.y+bb); o.z=gelu_f(s.z+bb); o.w=gelu_f(s.w+bb);
        ((float4*)t1)[(size_t)co*8192 + (b<<10) + q4base + fi] = o;
    }

    // ---- bank build (one block only) ----
    if(bln==0){
        __shared__ float ridge[648];
        __shared__ float pmS[8], pdenS[8];
        for(int t=tid;t<648;t+=256){
            int p=t/81, idx=t-p*81;
            int i=idx/9, j=idx-i*9;
            float ay=-1.f+0.25f*(float)i;
            float ax=-1.f+0.25f*(float)j;
            float ang=2.f*PI_F*(float)p*0.125f;
            const float Ls[3]={0.45f,0.75f,1.05f};
            const float Ws[3]={0.14f,0.20f,0.28f};
            float L=Ls[p%3], Wd=Ws[(p/3)%3];
            float cs=cosf(ang), sn=sinf(ang);
            float xr=ax*cs+ay*sn;
            float yr=-ax*sn+ay*cs;
            float tp=1.f-fminf(fabsf(xr)/L,1.f);
            float taper=powf(tp,1.5f);
            float core=expf(-0.5f*((xr/L)*(xr/L)+(yr/Wd)*(yr/Wd)));
            ridge[t]=taper*core*fmaxf(1.f-(yr/Wd)*(yr/Wd),0.f);
        }
        __syncthreads();
        {
            int p=tid>>5, k=tid&31;
            float s=0.f;
            for(int e=k;e<81;e+=32) s+=ridge[p*81+e];
            for(int off=16;off>0;off>>=1) s+=__shfl_down(s,off,32);
            if(k==0) pmS[p]=s*(1.f/81.f);
        }
        __syncthreads();
        {
            int p=tid>>5, k=tid&31;
            float m=pmS[p];
            float s=0.f;
            for(int e=k;e<81;e+=32) s+=fabsf(ridge[p*81+e]-m);
            for(int off=16;off>0;off>>=1) s+=__shfl_down(s,off,32);
            if(k==0) pdenS[p]=fmaxf(s,1e-6f);
        }
        __syncthreads();
        for(int t=tid;t<648;t+=256){
            int p=t/81;
            klg[t]=(ridge[t]-pmS[p])/pdenS[p]+0.05f*pd[t];
        }
    }
}

// ---------------- k_conv2: 3x3 conv 8->8 from t1 -> carrier, cm, absc ----------------
// grid 512: bl = b*64 + y, ONE output row per block
__global__ void __launch_bounds__(256) k_conv2(const float* __restrict__ t1,
    const float* __restrict__ w2, const float* __restrict__ b2,
    float* __restrict__ carrier, float* __restrict__ cm, float* __restrict__ absc,
    float* __restrict__ bpart){
    __shared__ float t1T[8][3][64];  // rows y-1..y+1, 6 KB
    __shared__ float w2s[576];
    __shared__ float sumS[4][64];
    __shared__ float saS[4][64];
    int tid=threadIdx.x, bl=blockIdx.x;
    int b=bl>>6, y=bl&63;
    for(int i=tid;i<576;i+=256) w2s[i]=w2[i];
    // stage t1 rows y-1..y+1 (8 ci x 3 rows x 64) — plain copy, t1 already gelu'd
    for(int j=tid;j<1536;j+=256){
        int ci=j/192, rem=j-ci*192, r=rem>>6, x=rem&63;
        int gy=y-1+r;
        float v=0.f;
        if(gy>=0 && gy<64){
            v = t1[(size_t)ci*32768 + (b<<12)+(gy<<6)+x];
        }
        t1T[ci][r][x]=v;
    }
    __syncthreads();
    int x=tid&63, cg=tid>>6;   // cg 0..3, each owns 2 output channels
    float acc[2];
    #pragma unroll
    for(int qq=0;qq<2;qq++) acc[qq]=b2[cg*2+qq];
    for(int ci=0;ci<8;ci++){
        #pragma unroll
        for(int r=0;r<3;r++){
            #pragma unroll
            for(int dx=-1;dx<=1;dx++){
                int xx=x+dx;
                float v=(xx>=0&&xx<64)?t1T[ci][r][xx]:0.f;
                int ti=r*3+(dx+1);
                #pragma unroll
                for(int qq=0;qq<2;qq++) acc[qq]+=v*w2s[(((cg*2+qq)*8+ci)*9)+ti];
            }
        }
    }
    float s2=0.f, sa2=0.f;
    #pragma unroll
    for(int qq=0;qq<2;qq++){
        float cv=gelu_f(acc[qq]);
        carrier[((size_t)((b<<3)+cg*2+qq)<<12)+(y<<6)+x]=cv;
        s2+=cv; sa2+=fabsf(cv);
    }
    sumS[cg][x]=s2; saS[cg][x]=sa2;
    __syncthreads();
    if(cg==0){   // tid 0..63 = wave 0
        float cmv=(sumS[0][x]+sumS[1][x]+sumS[2][x]+sumS[3][x])*0.125f;
        float av =(saS[0][x]+saS[1][x]+saS[2][x]+saS[3][x])*0.125f;
        int gp=(b<<12)+(y<<6)+x;
        cm[gp]=cmv;
        absc[gp]=av;
        float s=av, mn=av, mx=av;
        #pragma unroll
        for(int off=32;off>0;off>>=1){
            s += __shfl_down(s,off);
            mn = fminf(mn,__shfl_down(mn,off));
            mx = fmaxf(mx,__shfl_down(mx,off));
        }
        if(x==0){
            bpart[bl*8+0]=s;
            bpart[bl*8+3]=mn;
            bpart[bl*8+4]=mx;
        }
    }
}

// ---------------- k_resp: chp + 9x9 bank conv + csraw + top2 softmax ----------------
// grid 512: bl = b*64+y, ONE output row per block; 4 thread-groups x 2 protos
__global__ void __launch_bounds__(256) k_resp(const float* __restrict__ cm,
    const float* __restrict__ klg, const float* __restrict__ theta,
    const float* __restrict__ length, const float* __restrict__ width,
    const float* __restrict__ plog,
    float* __restrict__ csraw, float* __restrict__ ss0, float* __restrict__ bpart){
    __shared__ float cmT[704];       // rows y-5..y+5 (11 rows)
    __shared__ float chpT[576];      // rows y-4..y+4 (9 rows)
    __shared__ float klS[648];
    __shared__ float mg[64][16];
    int tid=threadIdx.x, bl=blockIdx.x;
    int b=bl>>6, y=bl&63;
    for(int i=tid;i<648;i+=256) klS[i]=klg[i];
    for(int j=tid;j<704;j+=256){
        int r=j>>6, x=j&63;
        int gy=y-5+r;
        cmT[j]=(gy>=0&&gy<64)?cm[(b<<12)+(gy<<6)+x]:0.f;
    }
    __syncthreads();
    for(int j=tid;j<576;j+=256){
        int rh=j>>6, x=j&63;      // rh 0..8 <-> gy = y-4+rh, cmT row rh+1
        int gy=y-4+rh;
        float v=0.f;
        if(gy>=0&&gy<64){
            float s=0.f;
            #pragma unroll
            for(int dy=0;dy<3;dy++){
                #pragma unroll
                for(int dx=-1;dx<=1;dx++){
                    int xx=x+dx;
                    if(xx>=0&&xx<64) s+=cmT[(rh+dy)*64+xx];
                }
            }
            v=cmT[(rh+1)*64+x]-s*(1.f/9.f);
        }
        chpT[j]=v;
    }
    __syncthreads();
    int x=tid&63, qg=tid>>6;   // qg 0..3, protos qg*2, qg*2+1
    int gp=(b<<12)+(y<<6)+x;
    float acc[2]={0.f,0.f};
    float cs=0.f;
    for(int dy=-4;dy<=4;dy++){
        int lr=dy+4;
        for(int dx=-4;dx<=4;dx++){
            int xx=x+dx;
            float v=(xx>=0&&xx<64)?chpT[lr*64+xx]:0.f;
            int ti=lr*9+(dx+4);
            acc[0]+=v*klS[(qg*2)*81+ti];
            acc[1]+=v*klS[(qg*2+1)*81+ti];
            if(qg==0 && dy>=-1&&dy<=1&&dx>=-1&&dx<=1) cs+=fabsf(v);
        }
    }
    float ta=tanhf(theta[gp])*PI_F;
    float lv=sigm_f(length[gp])*0.85f+0.25f;
    float wv=sigm_f(width[gp])*0.22f+0.08f;
    const float Ls[3]={0.45f,0.75f,1.05f};
    const float Ws[3]={0.14f,0.20f,0.28f};
    int pp=(y<<6)+x;
    float bias[2];
    #pragma unroll
    for(int qq=0;qq<2;qq++){
        int q=qg*2+qq;
        float ang=2.f*PI_F*(float)q*0.125f;
        float la=Ls[q%3], wa=Ws[(q/3)%3];
        bias[qq]=plog[((size_t)((b<<3)+q)<<12)+pp]
               +1.25f*cosf(ta-ang)
               -(lv-la)*(lv-la)*(1.f/0.08f)
               -(wv-wa)*(wv-wa)*(1.f/0.01f);
    }
    float m1,r1,m2,r2;
    if(bias[1]>bias[0]){ m1=bias[1];r1=acc[1]; m2=bias[0];r2=acc[0]; }
    else               { m1=bias[0];r1=acc[0]; m2=bias[1];r2=acc[1]; }
    mg[x][qg*4+0]=m1; mg[x][qg*4+1]=r1; mg[x][qg*4+2]=m2; mg[x][qg*4+3]=r2;
    __syncthreads();
    if(qg==0){   // wave 0
        float M1=mg[x][0],R1=mg[x][1],M2=mg[x][2],R2=mg[x][3];
        #pragma unroll
        for(int g=1;g<4;g++){
            float m1b=mg[x][g*4],r1b=mg[x][g*4+1],m2b=mg[x][g*4+2],r2b=mg[x][g*4+3];
            if(m1b>M1){
                float nM2,nR2;
                if(m2b>M1){nM2=m2b;nR2=r2b;} else {nM2=M1;nR2=R1;}
                M1=m1b;R1=r1b;M2=nM2;R2=nR2;
            } else if(m1b>M2){
                M2=m1b;R2=r1b;
            }
        }
        float e2=expf(M2-M1);
        float inv=1.0f/(1.0f+e2);
        ss0[gp]=R1*inv + R2*e2*inv;
        float csv=cs*(1.f/9.f);
        csraw[gp]=csv;
        float mn=csv, mx=csv;
        #pragma unroll
        for(int off=32;off>0;off>>=1){
            mn=fminf(mn,__shfl_down(mn,off));
            mx=fmaxf(mx,__shfl_down(mx,off));
        }
        if(x==0){
            bpart[bl*8+1]=mn;
            bpart[bl*8+2]=mx;
        }
    }
}

// ---------------- k_out: gate + h + pm2 fused; grid 512 (1 row / block) ----------------
__global__ void __launch_bounds__(256) k_out(const float* __restrict__ ss0,
    const float* __restrict__ csraw, const float* __restrict__ absc,
    const float* __restrict__ objn, const float* __restrict__ alpha,
    const float* __restrict__ theta, const float* __restrict__ curv,
    const float* __restrict__ carrier, const float* __restrict__ bpart,
    const float* __restrict__ w3, const float* __restrict__ b3,
    const float* __restrict__ w4, const float* __restrict__ b4,
    float* __restrict__ out){
    __shared__ float hS[8][64];      // 2 KB
    __shared__ float w4s[768*8];     // 24 KB
    __shared__ float b4s[768];
    __shared__ float wl3[96];
    __shared__ float bl3[8];
    __shared__ float evT[13*64];     // ev rows y-6..y+6
    __shared__ float gmT[13*64];     // sigm gate, same rows
    __shared__ float eT[9*64];       // erode rows y-4..y+4
    __shared__ float m1T[5*64];      // dilate rows y-2..y+2
    __shared__ float obT[3*64];      // sigm(objn) rows y-1..y+1
    __shared__ float red5[5];
    int tid=threadIdx.x;
    int bln=blockIdx.x;              // 0..511
    int b=bln>>6, y=bln&63;
    for(int i=tid;i<6144;i+=256) w4s[i]=w4[i];
    for(int i=tid;i<768;i+=256) b4s[i]=b4[i];
    if(tid<96) wl3[tid]=w3[tid];
    if(tid<8) bl3[tid]=b3[tid];
    // ---- batch stats reduction (wave 0) ----
    if(tid<64){
        const float* bp=&bpart[((size_t)b*64+tid)*8];
        float sm=bp[0], cmn=bp[1], cmx=bp[2], amn=bp[3], amx=bp[4];
        #pragma unroll
        for(int off=32;off>0;off>>=1){
            sm  += __shfl_down(sm,off);
            cmn  = fminf(cmn,__shfl_down(cmn,off));
            cmx  = fmaxf(cmx,__shfl_down(cmx,off));
            amn  = fminf(amn,__shfl_down(amn,off));
            amx  = fmaxf(amx,__shfl_down(amx,off));
        }
        if(tid==0){
            float den=fmaxf(sm*(1.0f/4096.0f),1e-6f);
            red5[0]=den; red5[1]=cmn; red5[2]=cmx; red5[3]=amn/den; red5[4]=amx/den;
        }
    }
    __syncthreads();
    float den=red5[0], cmn=red5[1], dmn=red5[3];
    float cinv = 1.0f/fmaxf(red5[2]-cmn,1e-6f);
    float dinv = 1.0f/fmaxf(red5[4]-dmn,1e-6f);
    // ---- ev / gm tiles (13 rows), objn tile (3 rows) ----
    for(int j=tid;j<832;j+=256){
        int r=j>>6, x=j&63; int gy=y-6+r;
        float ev=0.f;
        if(gy>=0&&gy<64){
            int gp=(b<<12)+(gy<<6)+x;
            float cs=(csraw[gp]-cmn)*cinv;
            float d=absc[gp]/den;
            ev=0.65f*cs+0.35f*((d-dmn)*dinv);
        }
        evT[j]=ev;
        gmT[j]=sigm_f((ev-0.2f)*(1.0f/0.08f));
    }
    for(int j=tid;j<192;j+=256){
        int r=j>>6,x=j&63; int gy=y-1+r;
        obT[j]=(gy>=0&&gy<64)?sigm_f(objn[(b<<12)+(gy<<6)+x]):0.f;
    }
    __syncthreads();
    // ---- erode rows y-4..y+4 ----
    for(int j=tid;j<576;j+=256){
        int r=j>>6,x=j&63; int gy=y-4+r;
        float m=0.f;
        if(gy>=0&&gy<64){
            m=1.f;
            for(int dy=-2;dy<=2;dy++){int yy=gy+dy; if(yy<0||yy>=64)continue;
                int lr=yy-(y-6);
                for(int dx=-2;dx<=2;dx++){int xx=x+dx; if(xx<0||xx>=64)continue;
                    if(evT[(lr<<6)+xx]<0.2f) m=0.f;}}
        }
        eT[j]=m;
    }
    __syncthreads();
    // ---- dilate e -> m1, rows y-2..y+2 ----
    for(int j=tid;j<320;j+=256){
        int r=j>>6,x=j&63; int gy=y-2+r;
        float m=0.f;
        if(gy>=0&&gy<64){
            m=-1e30f;
            for(int dy=-2;dy<=2;dy++){int yy=gy+dy; if(yy<0||yy>=64)continue;
                int lr=yy-(y-4);
                for(int dx=-2;dx<=2;dx++){int xx=x+dx; if(xx<0||xx>=64)continue;
                    m=fmaxf(m,eT[(lr<<6)+xx]);}}
        }
        m1T[j]=m;
    }
    __syncthreads();
    // ---- phase H: gate finish + h (wave 0, one thread per pixel of row y) ----
    if(tid<64){
        int x=tid;
        int gp=(b<<12)+(y<<6)+x;
        float m2=-1e30f, gx=-1e30f;
        for(int dy=-2;dy<=2;dy++){int yy=y+dy; if(yy<0||yy>=64)continue;
            int lr1=yy-(y-2), lr2=yy-(y-6);
            for(int dx=-2;dx<=2;dx++){int xx=x+dx; if(xx<0||xx>=64)continue;
                m2=fmaxf(m2,m1T[(lr1<<6)+xx]);
                gx=fmaxf(gx,gmT[(lr2<<6)+xx]);}}
        float s=0.f;
        for(int dy=-1;dy<=1;dy++){int yy=y+dy; if(yy<0||yy>=64)continue;
            int lr=yy-(y-1);
            for(int dx=-1;dx<=1;dx++){int xx=x+dx; if(xx<0||xx>=64)continue;
                s+=obT[(lr<<6)+xx];}}
        float blob=s*(1.0f/9.0f);
        float gate=gx*m2;
        float d=absc[gp]/den;
        float sgv=sigm_f(alpha[gp])*blob*gate*(0.7f+0.3f*fminf(fmaxf(d,0.f),2.f));
        // h
        const float* base = ss0 + (b<<12);
        float ssum=0.f;
        for(int dy=-1;dy<=1;dy++){int yy=y+dy; if(yy<0||yy>=64)continue;
            for(int dx=-1;dx<=1;dx++){int xx=x+dx;if(xx<0||xx>=64)continue;
                ssum+=base[(yy<<6)+xx];}}
        float ss1 = base[(y<<6)+x]-ssum*(1.0f/9.0f);
        float cu = tanhf(curv[gp]);
        float ssv = sgv*ss1*(1.0f+0.15f*cu);
        float ta = tanhf(theta[gp])*PI_F;
        float dxv=cosf(ta), dyv=sinf(ta);
        float car[8];
        #pragma unroll
        for(int ci=0;ci<8;ci++) car[ci]=carrier[((size_t)((b<<3)+ci)<<12)+(y<<6)+x];
        #pragma unroll
        for(int co=0;co<8;co++){
            const float* w=&wl3[co*12];
            float t = w[8] + w[9]*dxv + w[10]*dyv + w[11]*cu;
            #pragma unroll
            for(int ci=0;ci<8;ci++) t += w[ci]*car[ci];
            hS[co][tid] = gelu_f(bl3[co] + ssv*t);
        }
    }
    __syncthreads();
    // ---- phase 2: 8->768 expansion, NT stores ----
    int px4 = tid&15;          // f4 px within block
    int cg = tid>>4;           // 0..15, 48 co each
    int q0 = bln*16 + px4;     // GLOBAL f4 index (0..8191)
    int bb_ = q0>>10;
    int ql = q0 & 1023;        // within-batch f4 index
    float4 hv[8];
    #pragma unroll
    for(int ci=0;ci<8;ci++) hv[ci]=*(const float4*)&hS[ci][px4<<2];
    float4* o4=(float4*)out;
    for(int k=0;k<48;k++){
        int co=cg*48+k;
        float bv=b4s[co];
        float4 o=make_float4(bv,bv,bv,bv);
        const float* w=&w4s[co<<3];
        #pragma unroll
        for(int ci=0;ci<8;ci++){
            float wv=w[ci];
            o.x+=wv*hv[ci].x; o.y+=wv*hv[ci].y; o.z+=wv*hv[ci].z; o.w+=wv*hv[ci].w;
        }
        nt_store4(&o4[(size_t)(bb_*768+co)*1024 + ql], o);
    }
}

extern "C" void kernel_launch(void* const* d_in, const int* in_sizes, int n_in,
                              void* d_out, int out_size, void* d_ws, size_t ws_size,
                              hipStream_t stream) {
    const float* fm     =(const float*)d_in[0];
    const float* theta  =(const float*)d_in[1];
    const float* length =(const float*)d_in[2];
    const float* width  =(const float*)d_in[3];
    const float* curv   =(const float*)d_in[4];
    const float* alpha  =(const float*)d_in[5];
    const float* objn   =(const float*)d_in[6];
    const float* plog   =(const float*)d_in[7];
    const float* fp1w   =(const float*)d_in[8];
    const float* fp1b   =(const float*)d_in[9];
    const float* fp2w   =(const float*)d_in[10];
    const float* fp2b   =(const float*)d_in[11];
    const float* pm1w   =(const float*)d_in[12];
    const float* pm1b   =(const float*)d_in[13];
    const float* pm2w   =(const float*)d_in[14];
    const float* pm2b   =(const float*)d_in[15];
    const float* pdelta =(const float*)d_in[16];

    float* ws=(float*)d_ws;
    float* t1      = ws;                  // 262144
    float* carrier = t1 + 262144;         // 262144
    float* absc    = carrier + 262144;    // 32768
    float* csraw   = absc + 32768;        // 32768
    float* ss0     = csraw + 32768;       // 32768
    float* cm      = ss0 + 32768;         // 32768
    float* bpart   = cm + 32768;          // 4096 (512 records x 8)
    float* klg     = bpart + 4096;        // 648
    float* out     = (float*)d_out;

    k_conv1<<<512, 256, 0, stream>>>(fm, fp1w, fp1b, pdelta, t1, klg);
    k_conv2<<<512, 256, 0, stream>>>(t1, fp2w, fp2b, carrier, cm, absc, bpart);
    k_resp <<<512, 256, 0, stream>>>(cm, klg, theta, length, width, plog,
                                     csraw, ss0, bpart);
    k_out  <<<512, 256, 0, stream>>>(ss0, csraw, absc, objn, alpha, theta, curv,
                                     carrier, bpart, pm1w, pm1b, pm2w, pm2b, out);
}